// Round 9
// baseline (449.487 us; speedup 1.0000x reference)
//
#include <hip/hip_runtime.h>

// ---------- types ----------
typedef float    f32x4 __attribute__((ext_vector_type(4)));
typedef short    bf16x8 __attribute__((ext_vector_type(8)));
typedef unsigned short u16;
typedef u16      u16x4 __attribute__((ext_vector_type(4)));
typedef unsigned u32;
typedef u32      u32x4 __attribute__((ext_vector_type(4)));

#define MFMA16(a, b, c) __builtin_amdgcn_mfma_f32_16x16x32_bf16((a), (b), (c), 0, 0, 0)

#define CCH 512          // channels
#define NPIX 4096        // 64*64 pixels
#define NHEAD 4
#define HC 128           // head channels
#define NSPLIT 4         // flash-decoding KV splits
#define KVCHUNK (NPIX / NSPLIT)
#define QK_SCALE 0.04419417382415922f   // 1/sqrt(512)  (repo quirk: full C)
#define LOG2E 1.4426950408889634f

__device__ __forceinline__ u16 f2b(float f) {
  unsigned u = __builtin_bit_cast(unsigned, f);
  u += 0x7FFFu + ((u >> 16) & 1u);      // RNE
  return (u16)(u >> 16);
}
__device__ __forceinline__ float b2f(u16 b) {
  return __builtin_bit_cast(float, ((unsigned)b) << 16);
}

__device__ __forceinline__ void gl_lds16(const u16* g, u16* l) {
  __builtin_amdgcn_global_load_lds((const __attribute__((address_space(1))) void*)g,
                                   (__attribute__((address_space(3))) void*)l, 16, 0, 0);
}

// ---------- 1. weights fp32 -> bf16 ----------
__global__ void wconv_k(const float* __restrict__ w0, const float* __restrict__ w1,
                        const float* __restrict__ w2, const float* __restrict__ w3,
                        u16* __restrict__ dst) {
  int m = blockIdx.y;
  const float* src = (m == 0) ? w0 : (m == 1) ? w1 : (m == 2) ? w2 : w3;
  int i = (blockIdx.x * 256 + threadIdx.x) * 4;
  f32x4 v = *(const f32x4*)(src + i);
  u16x4 o = { f2b(v[0]), f2b(v[1]), f2b(v[2]), f2b(v[3]) };
  *(u16x4*)(dst + (size_t)m * (CCH * CCH) + i) = o;
}

// ---------- 2. GroupNorm partial statistics: 4 chunks per (b, group) ----------
__global__ void gn_stats_k(const float* __restrict__ x, float* __restrict__ pstats) {
  int blk = blockIdx.x;                      // 0..255 = bg*4 + chunk
  const f32x4* p = (const f32x4*)(x + (size_t)blk * 16384);
  int t = threadIdx.x, wv = t >> 6, l = t & 63;
  float s = 0.f, ss = 0.f;
  for (int i = t; i < 4096; i += 256) {
    f32x4 v = p[i];
    s  += v[0] + v[1] + v[2] + v[3];
    ss += v[0]*v[0] + v[1]*v[1] + v[2]*v[2] + v[3]*v[3];
  }
  #pragma unroll
  for (int d = 32; d; d >>= 1) { s += __shfl_down(s, d, 64); ss += __shfl_down(ss, d, 64); }
  __shared__ float red[8];
  if (l == 0) { red[wv*2] = s; red[wv*2+1] = ss; }
  __syncthreads();
  if (t == 0) {
    pstats[blk*2]   = red[0] + red[2] + red[4] + red[6];
    pstats[blk*2+1] = red[1] + red[3] + red[5] + red[7];
  }
}

// ---------- 3. GN apply + transpose ----------
__global__ void gn_norm_k(const float* __restrict__ x, const float* __restrict__ gns,
                          const float* __restrict__ gnb, const float* __restrict__ pstats,
                          u16* __restrict__ Ht) {
  int t = threadIdx.x;
  int ct = blockIdx.x * 64, nt = blockIdx.y * 64, b = blockIdx.z;
  int c0 = ct + (t & 15) * 4;
  int n0 = nt + (t >> 4) * 4;
  const float* xb = x + ((size_t)b * CCH + c0) * NPIX + n0;
  int g = b * 32 + (c0 >> 4);
  const f32x4* ps = (const f32x4*)(pstats + g * 8);
  f32x4 p0 = ps[0], p1 = ps[1];
  float s  = p0[0] + p0[2] + p1[0] + p1[2];
  float ss = p0[1] + p0[3] + p1[1] + p1[3];
  float mean = s * (1.f/65536.f);
  float var  = ss * (1.f/65536.f) - mean*mean;
  float rstd = rsqrtf(var + 1e-6f);
  f32x4 rows[4];
  #pragma unroll
  for (int j = 0; j < 4; ++j) {
    f32x4 v = *(const f32x4*)(xb + (size_t)j * NPIX);
    float a  = rstd * gns[c0 + j];
    float bb = gnb[c0 + j] - mean * a;
    rows[j] = v * a + bb;
  }
  #pragma unroll
  for (int i = 0; i < 4; ++i) {
    u16x4 o = { f2b(rows[0][i]), f2b(rows[1][i]), f2b(rows[2][i]), f2b(rows[3][i]) };
    *(u16x4*)(Ht + ((size_t)b * NPIX + n0 + i) * CCH + c0) = o;
  }
}

// ---------- 4. NT GEMM ----------
// MODE 1: A=W, B=Ht[z]           -> outb[z][row=o][col=pix], bias[row]
// MODE 2: A=Wo, B=Ot[z], resid=x -> outf[z][row=o][col=pix] fp32
// MODE 3: A=Ht flat [8192][512], B=[wq;wk] stacked [1024][512]
//         gcol<512 -> outb=Qt (alpha, bias) ; else outb2=Kt (bias2)
template<int MODE>
__global__ __launch_bounds__(256) void gemm_nt(const u16* __restrict__ A,
                                               const u16* __restrict__ B,
                                               const float* __restrict__ bias,
                                               const float* __restrict__ bias2,
                                               u16* __restrict__ outb,
                                               u16* __restrict__ outb2,
                                               float* __restrict__ outf,
                                               const float* __restrict__ resid,
                                               float alpha) {
  __shared__ __align__(16) u16 As[128 * 32];
  __shared__ __align__(16) u16 Bs[128 * 32];
  const int t = threadIdx.x, l = t & 63, wv = t >> 6;
  const int l16 = l & 15, lq = l >> 4;
  const int mt = blockIdx.x * 128, nt = blockIdx.y * 128, z = blockIdx.z;
  const u16* Ap = A + (size_t)mt * CCH;
  const u16* Bp = (MODE == 3) ? (B + (size_t)nt * CCH)
                              : (B + ((size_t)z * NPIX + nt) * CCH);
  const int wm = (wv >> 1) * 64, wn = (wv & 1) * 64;
  f32x4 acc[4][4] = {};
  for (int k0 = 0; k0 < CCH; k0 += 32) {
    __syncthreads();
    #pragma unroll
    for (int j = 0; j < 2; ++j) {
      int idx = t + j * 256;
      int row = idx >> 2, kc = (idx & 3) * 8;
      gl_lds16(Ap + (size_t)row * CCH + k0 + kc, As + idx * 8);
      gl_lds16(Bp + (size_t)row * CCH + k0 + kc, Bs + idx * 8);
    }
    __syncthreads();
    bf16x8 af[4], bfr[4];
    #pragma unroll
    for (int i = 0; i < 4; ++i) {
      af[i]  = *(const bf16x8*)(As + (wm + i * 16 + l16) * 32 + lq * 8);
      bfr[i] = *(const bf16x8*)(Bs + (wn + i * 16 + l16) * 32 + lq * 8);
    }
    #pragma unroll
    for (int mi = 0; mi < 4; ++mi)
      #pragma unroll
      for (int ni = 0; ni < 4; ++ni)
        acc[mi][ni] = MFMA16(af[mi], bfr[ni], acc[mi][ni]);
  }
  #pragma unroll
  for (int mi = 0; mi < 4; ++mi)
    #pragma unroll
    for (int ni = 0; ni < 4; ++ni)
      #pragma unroll
      for (int r = 0; r < 4; ++r) {
        int grow = mt + wm + mi * 16 + lq * 4 + r;
        int gcol = nt + wn + ni * 16 + l16;
        float v = acc[mi][ni][r];
        if (MODE == 1) {
          outb[((size_t)z * CCH + grow) * NPIX + gcol] = f2b(v + bias[grow]);
        } else if (MODE == 2) {
          size_t off = ((size_t)z * CCH + grow) * NPIX + gcol;
          outf[off] = v + bias[grow] + resid[off];
        } else {  // MODE 3
          if (gcol < 512)
            outb[(size_t)grow * CCH + gcol] = f2b((v + bias[gcol]) * alpha);
          else
            outb2[(size_t)grow * CCH + (gcol - 512)] = f2b(v + bias2[gcol - 512]);
        }
      }
}

// ---------- 5. Flash attention: R6 schedule, K-only LDS dbuf (32KB), V from L2 ----------
// No-max softmax (S bounded; P=exp2(S) direct); denom via ones-MFMA.
// K double-buffered in LDS (2x16KB) with the proven simple schedule: stage K(t+1),
// QK(t), softmax, PV(t) with V read DIRECTLY from global (L2-resident 256KB/group),
// vmcnt(0)+syncthreads. 32KB LDS + VGPR<=128 -> 4 blocks/CU = 4 waves/SIMD.
__global__ __launch_bounds__(256, 4) void flash_k(const u16* __restrict__ Qt,
                                                  const u16* __restrict__ Kt,
                                                  const u16* __restrict__ Vc,
                                                  u16* __restrict__ sl0, u16* __restrict__ sl1,
                                                  u16* __restrict__ sl2, u16* __restrict__ sl3,
                                                  float* __restrict__ mlp) {
  __shared__ __align__(16) char lds[32768];
  const int t = threadIdx.x, wv = t >> 6, l = t & 63;
  const int l16 = l & 15, lq = l >> 4;
  const int orig = blockIdx.x;
  const int gid = (orig & 7) * 128 + (orig >> 3);    // XCD-chunked remap (1024%8==0)
  const int qx = gid & 31, grp = gid >> 5;           // 32 groups; 4 per XCD (~1MB hot/XCD)
  const int hd = grp & 3, b = (grp >> 2) & 1, s = grp >> 3;
  const int qt0 = qx * 128 + wv * 32;

  const u16* Q = Qt + ((size_t)b * NPIX + qt0) * CCH + hd * HC;
  const u16* Kbase = Kt + (size_t)b * NPIX * CCH + hd * HC;          // [key][CCH]
  const u16* Vbase = Vc + (size_t)b * CCH * NPIX + (size_t)hd * HC * NPIX; // [ch][NPIX]
  u16* slab = (s == 0) ? sl0 : (s == 1) ? sl1 : (s == 2) ? sl2 : sl3;
  u16* Ob = slab + ((size_t)(b * NHEAD + hd) * NPIX + qt0) * HC;
  size_t mlR0 = (size_t)s * 32768 + (size_t)(b * NHEAD + hd) * NPIX + qt0;

  bf16x8 qf[2][4];
  #pragma unroll
  for (int mi = 0; mi < 2; ++mi)
    #pragma unroll
    for (int kk = 0; kk < 4; ++kk)
      qf[mi][kk] = *(const bf16x8*)(Q + (size_t)(mi * 16 + l16) * CCH + kk * 32 + lq * 8);

  const int m_beg = s * KVCHUNK;
  const int sw = (l16 & 7) << 4;                    // per-lane swizzle nibble

  // ---- loop-invariant K ds_read bases (byte offsets into lds) ----
  int kbase[4];
  #pragma unroll
  for (int kk = 0; kk < 4; ++kk) kbase[kk] = l16 * 256 + ((kk * 64 + lq * 16) ^ sw);

  // ---- loop-invariant K stage granule offsets (elements) ----
  u32 kgo[4];
  #pragma unroll
  for (int j = 0; j < 4; ++j) {
    int g = j * 256 + t;
    int row = g >> 4, src = ((g & 15) << 4) ^ ((row & 7) << 4);
    kgo[j] = (u32)row * CCH + (src >> 1);
  }

  // ---- per-lane V global pointers (permuted key-base matches permlane order) ----
  const u16* vp[8];
  #pragma unroll
  for (int cc = 0; cc < 8; ++cc)
    vp[cc] = Vbase + (size_t)(cc * 16 + l16) * NPIX + m_beg + (lq & 1) * 16 + (lq >> 1) * 8;

  const short one_bf = (short)0x3F80;               // bf16 1.0
  const bf16x8 vones = { one_bf, one_bf, one_bf, one_bf, one_bf, one_bf, one_bf, one_bf };

  f32x4 oacc[2][8] = {};
  f32x4 osum[2] = {};                               // row-sum of P (softmax denom), via MFMA

  // ---- prologue: stage K(0) -> buf0 ----
  {
    const u16* kg = Kbase + (size_t)m_beg * CCH;
    #pragma unroll
    for (int j = 0; j < 4; ++j) gl_lds16(kg + kgo[j], (u16*)lds + (j * 256 + t) * 8);
  }
  asm volatile("s_waitcnt vmcnt(0)" ::: "memory");
  __syncthreads();

  const int NT = KVCHUNK / 64;                      // 16 (even)

#define FLASH_BODY(CUR, M0, DOSTAGE)                                                   \
  {                                                                                    \
    if (DOSTAGE) {                                                                     \
      const u16* kg = Kbase + (size_t)((M0) + 64) * CCH;                               \
      _Pragma("unroll")                                                                \
      for (int j = 0; j < 4; ++j)                                                      \
        gl_lds16(kg + kgo[j], (u16*)(lds + ((CUR) ^ 1) * 16384) + (j * 256 + t) * 8);  \
    }                                                                                  \
    f32x4 S[2][4] = {};                                                                \
    __builtin_amdgcn_s_setprio(1);                                                     \
    _Pragma("unroll")                                                                  \
    for (int kk = 0; kk < 4; ++kk)                                                     \
      _Pragma("unroll")                                                                \
      for (int mm = 0; mm < 4; ++mm) {                                                 \
        bf16x8 kf = *(const bf16x8*)(lds + kbase[kk] + mm * 4096 + (CUR) * 16384);     \
        S[0][mm] = MFMA16(kf, qf[0][kk], S[0][mm]);                                    \
        S[1][mm] = MFMA16(kf, qf[1][kk], S[1][mm]);                                    \
      }                                                                                \
    __builtin_amdgcn_s_setprio(0);                                                     \
    u32 pk[2][4][2];                                                                   \
    _Pragma("unroll")                                                                  \
    for (int mi = 0; mi < 2; ++mi) {                                                   \
      _Pragma("unroll")                                                                \
      for (int mm = 0; mm < 4; ++mm) {                                                 \
        f32x4 p;                                                                       \
        _Pragma("unroll")                                                              \
        for (int r = 0; r < 4; ++r) p[r] = exp2f(S[mi][mm][r]);                        \
        asm("v_cvt_pk_bf16_f32 %0, %1, %2" : "=v"(pk[mi][mm][0]) : "v"(p[0]), "v"(p[1])); \
        asm("v_cvt_pk_bf16_f32 %0, %1, %2" : "=v"(pk[mi][mm][1]) : "v"(p[2]), "v"(p[3])); \
      }                                                                                \
    }                                                                                  \
    bf16x8 pa[2][2];                                                                   \
    _Pragma("unroll")                                                                  \
    for (int mi = 0; mi < 2; ++mi)                                                     \
      _Pragma("unroll")                                                                \
      for (int ks = 0; ks < 2; ++ks) {                                                 \
        u32 a0 = pk[mi][2 * ks][0], a1 = pk[mi][2 * ks][1];                            \
        u32 b0 = pk[mi][2 * ks + 1][0], b1 = pk[mi][2 * ks + 1][1];                    \
        asm("v_permlane16_swap_b32 %0, %1" : "+v"(a0), "+v"(b0));                      \
        asm("v_permlane16_swap_b32 %0, %1" : "+v"(a1), "+v"(b1));                      \
        u32x4 w = { a0, a1, b0, b1 };                                                  \
        pa[mi][ks] = __builtin_bit_cast(bf16x8, w);                                    \
      }                                                                                \
    __builtin_amdgcn_s_setprio(1);                                                     \
    _Pragma("unroll")                                                                  \
    for (int ks = 0; ks < 2; ++ks) {                                                   \
      osum[0] = MFMA16(pa[0][ks], vones, osum[0]);                                     \
      osum[1] = MFMA16(pa[1][ks], vones, osum[1]);                                     \
      _Pragma("unroll")                                                                \
      for (int cc = 0; cc < 8; ++cc) {                                                 \
        bf16x8 vf = *(const bf16x8*)(vp[cc] + ks * 32);                                \
        oacc[0][cc] = MFMA16(pa[0][ks], vf, oacc[0][cc]);                              \
        oacc[1][cc] = MFMA16(pa[1][ks], vf, oacc[1][cc]);                              \
      }                                                                                \
    }                                                                                  \
    __builtin_amdgcn_s_setprio(0);                                                     \
    _Pragma("unroll")                                                                  \
    for (int cc = 0; cc < 8; ++cc) vp[cc] += 64;                                       \
    asm volatile("s_waitcnt vmcnt(0)" ::: "memory");                                   \
    __syncthreads();                                                                   \
  }

  for (int it = 0; it < NT; it += 2) {
    FLASH_BODY(0, m_beg + it * 64, true)                    // NT even: it+1 < NT always
    FLASH_BODY(1, m_beg + it * 64 + 64, (it + 2 < NT))
  }
#undef FLASH_BODY

  // ---- epilogue: raw partial O + denominator l ----
  #pragma unroll
  for (int mi = 0; mi < 2; ++mi)
    #pragma unroll
    for (int cc = 0; cc < 8; ++cc)
      #pragma unroll
      for (int r = 0; r < 4; ++r)
        Ob[(size_t)(mi * 16 + lq * 4 + r) * HC + cc * 16 + l16] = f2b(oacc[mi][cc][r]);
  if (l16 == 0) {
    #pragma unroll
    for (int mi = 0; mi < 2; ++mi)
      #pragma unroll
      for (int r = 0; r < 4; ++r)
        mlp[mlR0 + mi * 16 + lq * 4 + r] = osum[mi][r];
  }
}

// ---------- 6. split merge (4 splits, l-only weights) ----------
__global__ void merge_k(const u16* __restrict__ s0, const u16* __restrict__ s1,
                        const u16* __restrict__ s2, const u16* __restrict__ s3,
                        const float* __restrict__ ml, u16* __restrict__ Ot) {
  int t = threadIdx.x;
  int R = blockIdx.x * 32 + (t >> 3);        // row 0..32767 ([b][h][q])
  int ch = (t & 7) * 16;
  float L = ml[R] + ml[32768 + R] + ml[65536 + R] + ml[98304 + R];
  float inv = 1.f / L;
  float acc[16] = {};
  const u16* sp[4] = { s0, s1, s2, s3 };
  #pragma unroll
  for (int s = 0; s < 4; ++s) {
    const bf16x8* p = (const bf16x8*)(sp[s] + (size_t)R * HC + ch);
    #pragma unroll
    for (int j = 0; j < 2; ++j) {
      bf16x8 v = p[j];
      #pragma unroll
      for (int e = 0; e < 8; ++e) acc[j * 8 + e] += b2f((u16)v[e]);
    }
  }
  int b = R >> 14, h = (R >> 12) & 3, q = R & 4095;
  u16* o = Ot + ((size_t)((b << 12) + q) * CCH) + h * HC + ch;
  #pragma unroll
  for (int j = 0; j < 4; ++j) {
    u16x4 o4 = { f2b(acc[j*4] * inv), f2b(acc[j*4+1] * inv),
                 f2b(acc[j*4+2] * inv), f2b(acc[j*4+3] * inv) };
    *(u16x4*)(o + j * 4) = o4;
  }
}

// ---------- launch ----------
extern "C" void kernel_launch(void* const* d_in, const int* in_sizes, int n_in,
                              void* d_out, int out_size, void* d_ws, size_t ws_size,
                              hipStream_t stream) {
  const float* x   = (const float*)d_in[0];
  const float* gns = (const float*)d_in[1];
  const float* gnb = (const float*)d_in[2];
  const float* wq  = (const float*)d_in[3];
  const float* bq  = (const float*)d_in[4];
  const float* wk  = (const float*)d_in[5];
  const float* bk  = (const float*)d_in[6];
  const float* wv  = (const float*)d_in[7];
  const float* bv  = (const float*)d_in[8];
  const float* wo  = (const float*)d_in[9];
  const float* bo  = (const float*)d_in[10];
  float* out = (float*)d_out;
  char* ws = (char*)d_ws;

  u16*   wb    = (u16*)ws;                          // 4 x 512x512 bf16 = 2 MiB ([wq;wk] contiguous)
  u16*   Ht    = (u16*)(ws + (size_t)( 2u << 20));  // [2][4096][512] (dead after V gemm)
  u16*   Qt    = (u16*)(ws + (size_t)(10u << 20));
  u16*   Kt    = (u16*)(ws + (size_t)(18u << 20));
  u16*   Vc    = (u16*)(ws + (size_t)(26u << 20));  // [2][512][4096]
  u16*   Ot    = (u16*)(ws + (size_t)(34u << 20));
  float* mlb   = (float*)(ws + (size_t)(42u << 20)); // [4][32768] f32 = 512 KiB
  float* stats = (float*)(ws + (size_t)(43u << 20)); // pstats [256][2]
  u16*   sl3   = (u16*)(ws + (size_t)(44u << 20));   // 8 MiB -> peak ws 52 MiB
  // partial-O slabs in dead/overwritten-later space:
  u16*   sl0   = Ht;                                 // Ht dead after V gemm
  u16*   sl1   = (u16*)d_out;                        // d_out (16 MiB) holds sl1+sl2;
  u16*   sl2   = (u16*)((char*)d_out + (size_t)(8u << 20)); // consumed before final gemm writes

  wconv_k   <<<dim3(256, 4, 1), 256, 0, stream>>>(wq, wk, wv, wo, wb);
  gn_stats_k<<<dim3(256, 1, 1), 256, 0, stream>>>(x, stats);
  gn_norm_k <<<dim3(8, 64, 2),  256, 0, stream>>>(x, gns, gnb, stats, Ht);
  gemm_nt<3><<<dim3(64, 8, 1),  256, 0, stream>>>(Ht, wb, bq, bk, Qt, Kt, nullptr, nullptr,
                                                  QK_SCALE * LOG2E);
  gemm_nt<1><<<dim3(4, 32, 2),  256, 0, stream>>>(wb + 2u * 262144u, Ht, bv, nullptr, Vc, nullptr,
                                                  nullptr, nullptr, 1.0f);
  flash_k   <<<dim3(1024, 1, 1), 256, 0, stream>>>(Qt, Kt, Vc, sl0, sl1, sl2, sl3, mlb);
  merge_k   <<<dim3(1024, 1, 1),256, 0, stream>>>(sl0, sl1, sl2, sl3, mlb, Ot);
  gemm_nt<2><<<dim3(4, 32, 2),  256, 0, stream>>>(wb + 3u * 262144u, Ot, bo, nullptr, nullptr,
                                                  nullptr, out, x, 1.0f);
}

// Round 10
// 156.303 us; speedup vs baseline: 2.8757x; 2.8757x over previous
//
#include <hip/hip_runtime.h>

// ---------- types ----------
typedef float    f32x4 __attribute__((ext_vector_type(4)));
typedef short    bf16x8 __attribute__((ext_vector_type(8)));
typedef unsigned short u16;
typedef u16      u16x4 __attribute__((ext_vector_type(4)));
typedef unsigned u32;
typedef u32      u32x4 __attribute__((ext_vector_type(4)));

#define MFMA16(a, b, c) __builtin_amdgcn_mfma_f32_16x16x32_bf16((a), (b), (c), 0, 0, 0)

#define CCH 512          // channels
#define NPIX 4096        // 64*64 pixels
#define NHEAD 4
#define HC 128           // head channels
#define NSPLIT 2         // flash-decoding KV splits
#define KVCHUNK (NPIX / NSPLIT)
#define QK_SCALE 0.04419417382415922f   // 1/sqrt(512)  (repo quirk: full C)
#define LOG2E 1.4426950408889634f

__device__ __forceinline__ u16 f2b(float f) {
  unsigned u = __builtin_bit_cast(unsigned, f);
  u += 0x7FFFu + ((u >> 16) & 1u);      // RNE
  return (u16)(u >> 16);
}
__device__ __forceinline__ float b2f(u16 b) {
  return __builtin_bit_cast(float, ((unsigned)b) << 16);
}

__device__ __forceinline__ void gl_lds16(const u16* g, u16* l) {
  __builtin_amdgcn_global_load_lds((const __attribute__((address_space(1))) void*)g,
                                   (__attribute__((address_space(3))) void*)l, 16, 0, 0);
}

// ---------- 1. weights fp32 -> bf16 ----------
__global__ void wconv_k(const float* __restrict__ w0, const float* __restrict__ w1,
                        const float* __restrict__ w2, const float* __restrict__ w3,
                        u16* __restrict__ dst) {
  int m = blockIdx.y;
  const float* src = (m == 0) ? w0 : (m == 1) ? w1 : (m == 2) ? w2 : w3;
  int i = (blockIdx.x * 256 + threadIdx.x) * 4;
  f32x4 v = *(const f32x4*)(src + i);
  u16x4 o = { f2b(v[0]), f2b(v[1]), f2b(v[2]), f2b(v[3]) };
  *(u16x4*)(dst + (size_t)m * (CCH * CCH) + i) = o;
}

// ---------- 2. GroupNorm partial statistics: 4 chunks per (b, group) ----------
__global__ void gn_stats_k(const float* __restrict__ x, float* __restrict__ pstats) {
  int blk = blockIdx.x;                      // 0..255 = bg*4 + chunk
  const f32x4* p = (const f32x4*)(x + (size_t)blk * 16384);
  int t = threadIdx.x, wv = t >> 6, l = t & 63;
  float s = 0.f, ss = 0.f;
  for (int i = t; i < 4096; i += 256) {
    f32x4 v = p[i];
    s  += v[0] + v[1] + v[2] + v[3];
    ss += v[0]*v[0] + v[1]*v[1] + v[2]*v[2] + v[3]*v[3];
  }
  #pragma unroll
  for (int d = 32; d; d >>= 1) { s += __shfl_down(s, d, 64); ss += __shfl_down(ss, d, 64); }
  __shared__ float red[8];
  if (l == 0) { red[wv*2] = s; red[wv*2+1] = ss; }
  __syncthreads();
  if (t == 0) {
    pstats[blk*2]   = red[0] + red[2] + red[4] + red[6];
    pstats[blk*2+1] = red[1] + red[3] + red[5] + red[7];
  }
}

// ---------- 3. GN apply + transpose ----------
__global__ void gn_norm_k(const float* __restrict__ x, const float* __restrict__ gns,
                          const float* __restrict__ gnb, const float* __restrict__ pstats,
                          u16* __restrict__ Ht) {
  int t = threadIdx.x;
  int ct = blockIdx.x * 64, nt = blockIdx.y * 64, b = blockIdx.z;
  int c0 = ct + (t & 15) * 4;
  int n0 = nt + (t >> 4) * 4;
  const float* xb = x + ((size_t)b * CCH + c0) * NPIX + n0;
  int g = b * 32 + (c0 >> 4);
  const f32x4* ps = (const f32x4*)(pstats + g * 8);
  f32x4 p0 = ps[0], p1 = ps[1];
  float s  = p0[0] + p0[2] + p1[0] + p1[2];
  float ss = p0[1] + p0[3] + p1[1] + p1[3];
  float mean = s * (1.f/65536.f);
  float var  = ss * (1.f/65536.f) - mean*mean;
  float rstd = rsqrtf(var + 1e-6f);
  f32x4 rows[4];
  #pragma unroll
  for (int j = 0; j < 4; ++j) {
    f32x4 v = *(const f32x4*)(xb + (size_t)j * NPIX);
    float a  = rstd * gns[c0 + j];
    float bb = gnb[c0 + j] - mean * a;
    rows[j] = v * a + bb;
  }
  #pragma unroll
  for (int i = 0; i < 4; ++i) {
    u16x4 o = { f2b(rows[0][i]), f2b(rows[1][i]), f2b(rows[2][i]), f2b(rows[3][i]) };
    *(u16x4*)(Ht + ((size_t)b * NPIX + n0 + i) * CCH + c0) = o;
  }
}

// ---------- 4. NT GEMM ----------
// MODE 1: A=W, B=Ht[z]           -> outb[z][row=o][col=pix], bias[row]
// MODE 2: A=Wo, B=Ot[z], resid=x -> outf[z][row=o][col=pix] fp32
// MODE 3: A=Ht flat [8192][512], B=[wq;wk] stacked [1024][512]
//         gcol<512 -> outb=Qt (alpha, bias) ; else outb2=Kt (bias2)
template<int MODE>
__global__ __launch_bounds__(256) void gemm_nt(const u16* __restrict__ A,
                                               const u16* __restrict__ B,
                                               const float* __restrict__ bias,
                                               const float* __restrict__ bias2,
                                               u16* __restrict__ outb,
                                               u16* __restrict__ outb2,
                                               float* __restrict__ outf,
                                               const float* __restrict__ resid,
                                               float alpha) {
  __shared__ __align__(16) u16 As[128 * 32];
  __shared__ __align__(16) u16 Bs[128 * 32];
  const int t = threadIdx.x, l = t & 63, wv = t >> 6;
  const int l16 = l & 15, lq = l >> 4;
  const int mt = blockIdx.x * 128, nt = blockIdx.y * 128, z = blockIdx.z;
  const u16* Ap = A + (size_t)mt * CCH;
  const u16* Bp = (MODE == 3) ? (B + (size_t)nt * CCH)
                              : (B + ((size_t)z * NPIX + nt) * CCH);
  const int wm = (wv >> 1) * 64, wn = (wv & 1) * 64;
  f32x4 acc[4][4] = {};
  for (int k0 = 0; k0 < CCH; k0 += 32) {
    __syncthreads();
    #pragma unroll
    for (int j = 0; j < 2; ++j) {
      int idx = t + j * 256;
      int row = idx >> 2, kc = (idx & 3) * 8;
      gl_lds16(Ap + (size_t)row * CCH + k0 + kc, As + idx * 8);
      gl_lds16(Bp + (size_t)row * CCH + k0 + kc, Bs + idx * 8);
    }
    __syncthreads();
    bf16x8 af[4], bfr[4];
    #pragma unroll
    for (int i = 0; i < 4; ++i) {
      af[i]  = *(const bf16x8*)(As + (wm + i * 16 + l16) * 32 + lq * 8);
      bfr[i] = *(const bf16x8*)(Bs + (wn + i * 16 + l16) * 32 + lq * 8);
    }
    #pragma unroll
    for (int mi = 0; mi < 4; ++mi)
      #pragma unroll
      for (int ni = 0; ni < 4; ++ni)
        acc[mi][ni] = MFMA16(af[mi], bfr[ni], acc[mi][ni]);
  }
  #pragma unroll
  for (int mi = 0; mi < 4; ++mi)
    #pragma unroll
    for (int ni = 0; ni < 4; ++ni)
      #pragma unroll
      for (int r = 0; r < 4; ++r) {
        int grow = mt + wm + mi * 16 + lq * 4 + r;
        int gcol = nt + wn + ni * 16 + l16;
        float v = acc[mi][ni][r];
        if (MODE == 1) {
          outb[((size_t)z * CCH + grow) * NPIX + gcol] = f2b(v + bias[grow]);
        } else if (MODE == 2) {
          size_t off = ((size_t)z * CCH + grow) * NPIX + gcol;
          outf[off] = v + bias[grow] + resid[off];
        } else {  // MODE 3
          if (gcol < 512)
            outb[(size_t)grow * CCH + gcol] = f2b((v + bias[gcol]) * alpha);
          else
            outb2[(size_t)grow * CCH + (gcol - 512)] = f2b(v + bias2[gcol - 512]);
        }
      }
}

// ---------- 5. Flash attention (proven R6 structure) ----------
// No-max softmax: S (log2-domain, scale folded in Q) is bounded (86-sigma margin),
// so P = exp2(S) directly; denominator l = sum_k P via ones-B MFMA on matrix pipe.
// K+V double-buffered in 64KB LDS; one stage + one vmcnt(0)+syncthreads per tile.
// Flat LDS: [K buf0 16K][K buf1 16K][V buf0 16K][V buf1 16K]; ds_read addrs are
// loop-invariant base + compile-time offset (x2 unroll makes buffer idx constant).
__global__ __launch_bounds__(256, 2) void flash_k(const u16* __restrict__ Qt,
                                                  const u16* __restrict__ Kt,
                                                  const u16* __restrict__ Vc,
                                                  u16* __restrict__ sl0, u16* __restrict__ sl1,
                                                  float* __restrict__ mlp) {
  __shared__ __align__(16) char lds[65536];
  const int t = threadIdx.x, wv = t >> 6, l = t & 63;
  const int l16 = l & 15, lq = l >> 4;
  const int orig = blockIdx.x;
  const int gid = (orig & 7) * 64 + (orig >> 3);     // XCD-chunked remap (512%8==0)
  const int qx = gid & 31, grp = gid >> 5;
  const int hd = grp & 3, b = (grp >> 2) & 1, s = grp >> 3;
  const int qt0 = qx * 128 + wv * 32;

  const u16* Q = Qt + ((size_t)b * NPIX + qt0) * CCH + hd * HC;
  const u16* Kbase = Kt + (size_t)b * NPIX * CCH + hd * HC;          // [key][CCH]
  const u16* Vbase = Vc + (size_t)b * CCH * NPIX + (size_t)hd * HC * NPIX; // [ch][NPIX]
  u16* slab = (s == 0) ? sl0 : sl1;
  u16* Ob = slab + ((size_t)(b * NHEAD + hd) * NPIX + qt0) * HC;
  size_t mlR0 = (size_t)s * 32768 + (size_t)(b * NHEAD + hd) * NPIX + qt0;

  bf16x8 qf[2][4];
  #pragma unroll
  for (int mi = 0; mi < 2; ++mi)
    #pragma unroll
    for (int kk = 0; kk < 4; ++kk)
      qf[mi][kk] = *(const bf16x8*)(Q + (size_t)(mi * 16 + l16) * CCH + kk * 32 + lq * 8);

  const int m_beg = s * KVCHUNK;
  const int sw = (l16 & 7) << 4;                    // per-lane swizzle nibble
  const int vb2 = (lq & 1) * 32 + (lq >> 1) * 16;   // permuted key-base (permlane order)

  // ---- loop-invariant ds_read bases (byte offsets into lds) ----
  int kbase[4], vbase[2];
  #pragma unroll
  for (int kk = 0; kk < 4; ++kk) kbase[kk] = l16 * 256 + ((kk * 64 + lq * 16) ^ sw);
  #pragma unroll
  for (int ks = 0; ks < 2; ++ks) vbase[ks] = 32768 + l16 * 128 + ((ks * 64 + vb2) ^ sw);

  // ---- loop-invariant stage granule offsets (elements) ----
  u32 kgo[4], vgo[4];
  #pragma unroll
  for (int j = 0; j < 4; ++j) {
    int g = j * 256 + t;
    { int row = g >> 4, src = ((g & 15) << 4) ^ ((row & 7) << 4);
      kgo[j] = (u32)row * CCH + (src >> 1); }
    { int row = g >> 3, src = ((g & 7) << 4) ^ ((row & 7) << 4);
      vgo[j] = (u32)row * NPIX + (src >> 1); }
  }

  const short one_bf = (short)0x3F80;               // bf16 1.0
  const bf16x8 vones = { one_bf, one_bf, one_bf, one_bf, one_bf, one_bf, one_bf, one_bf };

  f32x4 oacc[2][8] = {};
  f32x4 osum[2] = {};                               // row-sum of P (softmax denom), via MFMA

  // ---- prologue: stage tile 0 into buf 0 ----
  {
    const u16* kg = Kbase + (size_t)m_beg * CCH;
    const u16* vg = Vbase + m_beg;
    #pragma unroll
    for (int j = 0; j < 4; ++j) {
      gl_lds16(kg + kgo[j], (u16*)lds + (j * 256 + t) * 8);
      gl_lds16(vg + vgo[j], (u16*)(lds + 32768) + (j * 256 + t) * 8);
    }
  }
  asm volatile("s_waitcnt vmcnt(0)" ::: "memory");
  __syncthreads();

  const int NT = KVCHUNK / 64;                      // 32 (even)

#define FLASH_BODY(CUR, M0, DOSTAGE)                                                   \
  {                                                                                    \
    if (DOSTAGE) {                                                                     \
      const u16* kg = Kbase + (size_t)((M0) + 64) * CCH;                               \
      const u16* vg = Vbase + ((M0) + 64);                                             \
      _Pragma("unroll")                                                                \
      for (int j = 0; j < 4; ++j) {                                                    \
        gl_lds16(kg + kgo[j], (u16*)(lds + ((CUR) ^ 1) * 16384) + (j * 256 + t) * 8);  \
        gl_lds16(vg + vgo[j], (u16*)(lds + 32768 + ((CUR) ^ 1) * 16384) + (j * 256 + t) * 8); \
      }                                                                                \
    }                                                                                  \
    f32x4 S[2][4] = {};                                                                \
    __builtin_amdgcn_s_setprio(1);                                                     \
    _Pragma("unroll")                                                                  \
    for (int kk = 0; kk < 4; ++kk)                                                     \
      _Pragma("unroll")                                                                \
      for (int mm = 0; mm < 4; ++mm) {                                                 \
        bf16x8 kf = *(const bf16x8*)(lds + kbase[kk] + mm * 4096 + (CUR) * 16384);     \
        S[0][mm] = MFMA16(kf, qf[0][kk], S[0][mm]);                                    \
        S[1][mm] = MFMA16(kf, qf[1][kk], S[1][mm]);                                    \
      }                                                                                \
    __builtin_amdgcn_s_setprio(0);                                                     \
    u32 pk[2][4][2];                                                                   \
    _Pragma("unroll")                                                                  \
    for (int mi = 0; mi < 2; ++mi) {                                                   \
      _Pragma("unroll")                                                                \
      for (int mm = 0; mm < 4; ++mm) {                                                 \
        f32x4 p;                                                                       \
        _Pragma("unroll")                                                              \
        for (int r = 0; r < 4; ++r) p[r] = exp2f(S[mi][mm][r]);                        \
        asm("v_cvt_pk_bf16_f32 %0, %1, %2" : "=v"(pk[mi][mm][0]) : "v"(p[0]), "v"(p[1])); \
        asm("v_cvt_pk_bf16_f32 %0, %1, %2" : "=v"(pk[mi][mm][1]) : "v"(p[2]), "v"(p[3])); \
      }                                                                                \
    }                                                                                  \
    bf16x8 pa[2][2];                                                                   \
    _Pragma("unroll")                                                                  \
    for (int mi = 0; mi < 2; ++mi)                                                     \
      _Pragma("unroll")                                                                \
      for (int ks = 0; ks < 2; ++ks) {                                                 \
        u32 a0 = pk[mi][2 * ks][0], a1 = pk[mi][2 * ks][1];                            \
        u32 b0 = pk[mi][2 * ks + 1][0], b1 = pk[mi][2 * ks + 1][1];                    \
        asm("v_permlane16_swap_b32 %0, %1" : "+v"(a0), "+v"(b0));                      \
        asm("v_permlane16_swap_b32 %0, %1" : "+v"(a1), "+v"(b1));                      \
        u32x4 w = { a0, a1, b0, b1 };                                                  \
        pa[mi][ks] = __builtin_bit_cast(bf16x8, w);                                    \
      }                                                                                \
    __builtin_amdgcn_s_setprio(1);                                                     \
    _Pragma("unroll")                                                                  \
    for (int ks = 0; ks < 2; ++ks) {                                                   \
      osum[0] = MFMA16(pa[0][ks], vones, osum[0]);                                     \
      osum[1] = MFMA16(pa[1][ks], vones, osum[1]);                                     \
      _Pragma("unroll")                                                                \
      for (int cc = 0; cc < 8; ++cc) {                                                 \
        bf16x8 vf = *(const bf16x8*)(lds + vbase[ks] + cc * 2048 + (CUR) * 16384);     \
        oacc[0][cc] = MFMA16(pa[0][ks], vf, oacc[0][cc]);                              \
        oacc[1][cc] = MFMA16(pa[1][ks], vf, oacc[1][cc]);                              \
      }                                                                                \
    }                                                                                  \
    __builtin_amdgcn_s_setprio(0);                                                     \
    asm volatile("s_waitcnt vmcnt(0)" ::: "memory");                                   \
    __syncthreads();                                                                   \
  }

  for (int it = 0; it < NT; it += 2) {
    FLASH_BODY(0, m_beg + it * 64, true)                    // NT even: it+1 < NT always
    FLASH_BODY(1, m_beg + it * 64 + 64, (it + 2 < NT))
  }
#undef FLASH_BODY

  // ---- epilogue: raw partial O + denominator l ----
  #pragma unroll
  for (int mi = 0; mi < 2; ++mi)
    #pragma unroll
    for (int cc = 0; cc < 8; ++cc)
      #pragma unroll
      for (int r = 0; r < 4; ++r)
        Ob[(size_t)(mi * 16 + lq * 4 + r) * HC + cc * 16 + l16] = f2b(oacc[mi][cc][r]);
  if (l16 == 0) {
    #pragma unroll
    for (int mi = 0; mi < 2; ++mi)
      #pragma unroll
      for (int r = 0; r < 4; ++r)
        mlp[mlR0 + mi * 16 + lq * 4 + r] = osum[mi][r];
  }
}

// ---------- 6. split merge (2 splits, l-only weights) ----------
__global__ void merge_k(const u16* __restrict__ s0, const u16* __restrict__ s1,
                        const float* __restrict__ ml, u16* __restrict__ Ot) {
  int t = threadIdx.x;
  int R = blockIdx.x * 32 + (t >> 3);        // row 0..32767 ([b][h][q])
  int ch = (t & 7) * 16;
  float L = ml[R] + ml[32768 + R];
  float inv = 1.f / L;
  float acc[16] = {};
  const u16* sp[2] = { s0, s1 };
  #pragma unroll
  for (int s = 0; s < 2; ++s) {
    const bf16x8* p = (const bf16x8*)(sp[s] + (size_t)R * HC + ch);
    #pragma unroll
    for (int j = 0; j < 2; ++j) {
      bf16x8 v = p[j];
      #pragma unroll
      for (int e = 0; e < 8; ++e) acc[j * 8 + e] += b2f((u16)v[e]);
    }
  }
  int b = R >> 14, h = (R >> 12) & 3, q = R & 4095;
  u16* o = Ot + ((size_t)((b << 12) + q) * CCH) + h * HC + ch;
  #pragma unroll
  for (int j = 0; j < 4; ++j) {
    u16x4 o4 = { f2b(acc[j*4] * inv), f2b(acc[j*4+1] * inv),
                 f2b(acc[j*4+2] * inv), f2b(acc[j*4+3] * inv) };
    *(u16x4*)(o + j * 4) = o4;
  }
}

// ---------- launch ----------
extern "C" void kernel_launch(void* const* d_in, const int* in_sizes, int n_in,
                              void* d_out, int out_size, void* d_ws, size_t ws_size,
                              hipStream_t stream) {
  const float* x   = (const float*)d_in[0];
  const float* gns = (const float*)d_in[1];
  const float* gnb = (const float*)d_in[2];
  const float* wq  = (const float*)d_in[3];
  const float* bq  = (const float*)d_in[4];
  const float* wk  = (const float*)d_in[5];
  const float* bk  = (const float*)d_in[6];
  const float* wv  = (const float*)d_in[7];
  const float* bv  = (const float*)d_in[8];
  const float* wo  = (const float*)d_in[9];
  const float* bo  = (const float*)d_in[10];
  float* out = (float*)d_out;
  char* ws = (char*)d_ws;

  u16*   wb    = (u16*)ws;                          // 4 x 512x512 bf16 = 2 MiB ([wq;wk] contiguous)
  u16*   Ht    = (u16*)(ws + (size_t)( 2u << 20));  // [2][4096][512] (dead after V gemm)
  u16*   Qt    = (u16*)(ws + (size_t)(10u << 20));
  u16*   Kt    = (u16*)(ws + (size_t)(18u << 20));
  u16*   Vc    = (u16*)(ws + (size_t)(26u << 20));  // [2][512][4096]
  u16*   Ot    = (u16*)(ws + (size_t)(34u << 20));
  float* mlb   = (float*)(ws + (size_t)(42u << 20)); // [2][32768] f32 = 256 KiB
  float* stats = (float*)(ws + (size_t)(43u << 20)); // pstats [256][2]
  // partial-O slabs in dead/overwritten-later space:
  u16*   sl0   = Ht;                                 // Ht dead after V gemm
  u16*   sl1   = (u16*)d_out;                        // consumed by merge before final gemm writes

  wconv_k   <<<dim3(256, 4, 1), 256, 0, stream>>>(wq, wk, wv, wo, wb);
  gn_stats_k<<<dim3(256, 1, 1), 256, 0, stream>>>(x, stats);
  gn_norm_k <<<dim3(8, 64, 2),  256, 0, stream>>>(x, gns, gnb, stats, Ht);
  gemm_nt<3><<<dim3(64, 8, 1),  256, 0, stream>>>(Ht, wb, bq, bk, Qt, Kt, nullptr, nullptr,
                                                  QK_SCALE * LOG2E);
  gemm_nt<1><<<dim3(4, 32, 2),  256, 0, stream>>>(wb + 2u * 262144u, Ht, bv, nullptr, Vc, nullptr,
                                                  nullptr, nullptr, 1.0f);
  flash_k   <<<dim3(512, 1, 1), 256, 0, stream>>>(Qt, Kt, Vc, sl0, sl1, mlb);
  merge_k   <<<dim3(1024, 1, 1),256, 0, stream>>>(sl0, sl1, mlb, Ot);
  gemm_nt<2><<<dim3(4, 32, 2),  256, 0, stream>>>(wb + 3u * 262144u, Ot, bo, nullptr, nullptr,
                                                  nullptr, out, x, 1.0f);
}

// Round 12
// 156.206 us; speedup vs baseline: 2.8775x; 1.0006x over previous
//
#include <hip/hip_runtime.h>

// ---------- types ----------
typedef float    f32x4 __attribute__((ext_vector_type(4)));
typedef short    bf16x8 __attribute__((ext_vector_type(8)));
typedef unsigned short u16;
typedef u16      u16x4 __attribute__((ext_vector_type(4)));
typedef unsigned u32;
typedef u32      u32x4 __attribute__((ext_vector_type(4)));

#define MFMA16(a, b, c) __builtin_amdgcn_mfma_f32_16x16x32_bf16((a), (b), (c), 0, 0, 0)

#define CCH 512          // channels
#define NPIX 4096        // 64*64 pixels
#define NHEAD 4
#define HC 128           // head channels
#define NSPLIT 2         // flash-decoding KV splits
#define KVCHUNK (NPIX / NSPLIT)
#define QK_SCALE 0.04419417382415922f   // 1/sqrt(512)  (repo quirk: full C)
#define LOG2E 1.4426950408889634f

__device__ __forceinline__ u16 f2b(float f) {
  unsigned u = __builtin_bit_cast(unsigned, f);
  u += 0x7FFFu + ((u >> 16) & 1u);      // RNE
  return (u16)(u >> 16);
}
__device__ __forceinline__ float b2f(u16 b) {
  return __builtin_bit_cast(float, ((unsigned)b) << 16);
}

__device__ __forceinline__ void gl_lds16(const u16* g, u16* l) {
  __builtin_amdgcn_global_load_lds((const __attribute__((address_space(1))) void*)g,
                                   (__attribute__((address_space(3))) void*)l, 16, 0, 0);
}

// ---------- 1. weights fp32 -> bf16 ----------
__global__ void wconv_k(const float* __restrict__ w0, const float* __restrict__ w1,
                        const float* __restrict__ w2, const float* __restrict__ w3,
                        u16* __restrict__ dst) {
  int m = blockIdx.y;
  const float* src = (m == 0) ? w0 : (m == 1) ? w1 : (m == 2) ? w2 : w3;
  int i = (blockIdx.x * 256 + threadIdx.x) * 4;
  f32x4 v = *(const f32x4*)(src + i);
  u16x4 o = { f2b(v[0]), f2b(v[1]), f2b(v[2]), f2b(v[3]) };
  *(u16x4*)(dst + (size_t)m * (CCH * CCH) + i) = o;
}

// ---------- 2. GroupNorm partial statistics: 4 chunks per (b, group) ----------
__global__ void gn_stats_k(const float* __restrict__ x, float* __restrict__ pstats) {
  int blk = blockIdx.x;                      // 0..255 = bg*4 + chunk
  const f32x4* p = (const f32x4*)(x + (size_t)blk * 16384);
  int t = threadIdx.x, wv = t >> 6, l = t & 63;
  float s = 0.f, ss = 0.f;
  for (int i = t; i < 4096; i += 256) {
    f32x4 v = p[i];
    s  += v[0] + v[1] + v[2] + v[3];
    ss += v[0]*v[0] + v[1]*v[1] + v[2]*v[2] + v[3]*v[3];
  }
  #pragma unroll
  for (int d = 32; d; d >>= 1) { s += __shfl_down(s, d, 64); ss += __shfl_down(ss, d, 64); }
  __shared__ float red[8];
  if (l == 0) { red[wv*2] = s; red[wv*2+1] = ss; }
  __syncthreads();
  if (t == 0) {
    pstats[blk*2]   = red[0] + red[2] + red[4] + red[6];
    pstats[blk*2+1] = red[1] + red[3] + red[5] + red[7];
  }
}

// ---------- 3. GN apply + transpose ----------
__global__ void gn_norm_k(const float* __restrict__ x, const float* __restrict__ gns,
                          const float* __restrict__ gnb, const float* __restrict__ pstats,
                          u16* __restrict__ Ht) {
  int t = threadIdx.x;
  int ct = blockIdx.x * 64, nt = blockIdx.y * 64, b = blockIdx.z;
  int c0 = ct + (t & 15) * 4;
  int n0 = nt + (t >> 4) * 4;
  const float* xb = x + ((size_t)b * CCH + c0) * NPIX + n0;
  int g = b * 32 + (c0 >> 4);
  const f32x4* ps = (const f32x4*)(pstats + g * 8);
  f32x4 p0 = ps[0], p1 = ps[1];
  float s  = p0[0] + p0[2] + p1[0] + p1[2];
  float ss = p0[1] + p0[3] + p1[1] + p1[3];
  float mean = s * (1.f/65536.f);
  float var  = ss * (1.f/65536.f) - mean*mean;
  float rstd = rsqrtf(var + 1e-6f);
  f32x4 rows[4];
  #pragma unroll
  for (int j = 0; j < 4; ++j) {
    f32x4 v = *(const f32x4*)(xb + (size_t)j * NPIX);
    float a  = rstd * gns[c0 + j];
    float bb = gnb[c0 + j] - mean * a;
    rows[j] = v * a + bb;
  }
  #pragma unroll
  for (int i = 0; i < 4; ++i) {
    u16x4 o = { f2b(rows[0][i]), f2b(rows[1][i]), f2b(rows[2][i]), f2b(rows[3][i]) };
    *(u16x4*)(Ht + ((size_t)b * NPIX + n0 + i) * CCH + c0) = o;
  }
}

// ---------- 4. NT GEMM (proven R10 version — 128x128 tiles) ----------
// MODE 1: A=W, B=Ht[z]           -> outb[z][row=o][col=pix], bias[row]
// MODE 2: A=Wo, B=Ot[z], resid=x -> outf[z][row=o][col=pix] fp32
// MODE 3: A=Ht flat [8192][512], B=[wq;wk] stacked [1024][512]
//         gcol<512 -> outb=Qt (alpha, bias) ; else outb2=Kt (bias2)
template<int MODE>
__global__ __launch_bounds__(256) void gemm_nt(const u16* __restrict__ A,
                                               const u16* __restrict__ B,
                                               const float* __restrict__ bias,
                                               const float* __restrict__ bias2,
                                               u16* __restrict__ outb,
                                               u16* __restrict__ outb2,
                                               float* __restrict__ outf,
                                               const float* __restrict__ resid,
                                               float alpha) {
  __shared__ __align__(16) u16 As[128 * 32];
  __shared__ __align__(16) u16 Bs[128 * 32];
  const int t = threadIdx.x, l = t & 63, wv = t >> 6;
  const int l16 = l & 15, lq = l >> 4;
  const int mt = blockIdx.x * 128, nt = blockIdx.y * 128, z = blockIdx.z;
  const u16* Ap = A + (size_t)mt * CCH;
  const u16* Bp = (MODE == 3) ? (B + (size_t)nt * CCH)
                              : (B + ((size_t)z * NPIX + nt) * CCH);
  const int wm = (wv >> 1) * 64, wn = (wv & 1) * 64;
  f32x4 acc[4][4] = {};
  for (int k0 = 0; k0 < CCH; k0 += 32) {
    __syncthreads();
    #pragma unroll
    for (int j = 0; j < 2; ++j) {
      int idx = t + j * 256;
      int row = idx >> 2, kc = (idx & 3) * 8;
      gl_lds16(Ap + (size_t)row * CCH + k0 + kc, As + idx * 8);
      gl_lds16(Bp + (size_t)row * CCH + k0 + kc, Bs + idx * 8);
    }
    __syncthreads();
    bf16x8 af[4], bfr[4];
    #pragma unroll
    for (int i = 0; i < 4; ++i) {
      af[i]  = *(const bf16x8*)(As + (wm + i * 16 + l16) * 32 + lq * 8);
      bfr[i] = *(const bf16x8*)(Bs + (wn + i * 16 + l16) * 32 + lq * 8);
    }
    #pragma unroll
    for (int mi = 0; mi < 4; ++mi)
      #pragma unroll
      for (int ni = 0; ni < 4; ++ni)
        acc[mi][ni] = MFMA16(af[mi], bfr[ni], acc[mi][ni]);
  }
  #pragma unroll
  for (int mi = 0; mi < 4; ++mi)
    #pragma unroll
    for (int ni = 0; ni < 4; ++ni)
      #pragma unroll
      for (int r = 0; r < 4; ++r) {
        int grow = mt + wm + mi * 16 + lq * 4 + r;
        int gcol = nt + wn + ni * 16 + l16;
        float v = acc[mi][ni][r];
        if (MODE == 1) {
          outb[((size_t)z * CCH + grow) * NPIX + gcol] = f2b(v + bias[grow]);
        } else if (MODE == 2) {
          size_t off = ((size_t)z * CCH + grow) * NPIX + gcol;
          outf[off] = v + bias[grow] + resid[off];
        } else {  // MODE 3
          if (gcol < 512)
            outb[(size_t)grow * CCH + gcol] = f2b((v + bias[gcol]) * alpha);
          else
            outb2[(size_t)grow * CCH + (gcol - 512)] = f2b(v + bias2[gcol - 512]);
        }
      }
}

// ---------- 5. Flash attention (proven R6 structure — unchanged) ----------
// No-max softmax: S (log2-domain, scale folded in Q) is bounded (86-sigma margin),
// so P = exp2(S) directly; denominator l = sum_k P via ones-B MFMA on matrix pipe.
// K+V double-buffered in 64KB LDS; one stage + one vmcnt(0)+syncthreads per tile.
__global__ __launch_bounds__(256, 2) void flash_k(const u16* __restrict__ Qt,
                                                  const u16* __restrict__ Kt,
                                                  const u16* __restrict__ Vc,
                                                  u16* __restrict__ sl0, u16* __restrict__ sl1,
                                                  float* __restrict__ mlp) {
  __shared__ __align__(16) char lds[65536];
  const int t = threadIdx.x, wv = t >> 6, l = t & 63;
  const int l16 = l & 15, lq = l >> 4;
  const int orig = blockIdx.x;
  const int gid = (orig & 7) * 64 + (orig >> 3);     // XCD-chunked remap (512%8==0)
  const int qx = gid & 31, grp = gid >> 5;
  const int hd = grp & 3, b = (grp >> 2) & 1, s = grp >> 3;
  const int qt0 = qx * 128 + wv * 32;

  const u16* Q = Qt + ((size_t)b * NPIX + qt0) * CCH + hd * HC;
  const u16* Kbase = Kt + (size_t)b * NPIX * CCH + hd * HC;          // [key][CCH]
  const u16* Vbase = Vc + (size_t)b * CCH * NPIX + (size_t)hd * HC * NPIX; // [ch][NPIX]
  u16* slab = (s == 0) ? sl0 : sl1;
  u16* Ob = slab + ((size_t)(b * NHEAD + hd) * NPIX + qt0) * HC;
  size_t mlR0 = (size_t)s * 32768 + (size_t)(b * NHEAD + hd) * NPIX + qt0;

  bf16x8 qf[2][4];
  #pragma unroll
  for (int mi = 0; mi < 2; ++mi)
    #pragma unroll
    for (int kk = 0; kk < 4; ++kk)
      qf[mi][kk] = *(const bf16x8*)(Q + (size_t)(mi * 16 + l16) * CCH + kk * 32 + lq * 8);

  const int m_beg = s * KVCHUNK;
  const int sw = (l16 & 7) << 4;                    // per-lane swizzle nibble
  const int vb2 = (lq & 1) * 32 + (lq >> 1) * 16;   // permuted key-base (permlane order)

  int kbase[4], vbase[2];
  #pragma unroll
  for (int kk = 0; kk < 4; ++kk) kbase[kk] = l16 * 256 + ((kk * 64 + lq * 16) ^ sw);
  #pragma unroll
  for (int ks = 0; ks < 2; ++ks) vbase[ks] = 32768 + l16 * 128 + ((ks * 64 + vb2) ^ sw);

  u32 kgo[4], vgo[4];
  #pragma unroll
  for (int j = 0; j < 4; ++j) {
    int g = j * 256 + t;
    { int row = g >> 4, src = ((g & 15) << 4) ^ ((row & 7) << 4);
      kgo[j] = (u32)row * CCH + (src >> 1); }
    { int row = g >> 3, src = ((g & 7) << 4) ^ ((row & 7) << 4);
      vgo[j] = (u32)row * NPIX + (src >> 1); }
  }

  const short one_bf = (short)0x3F80;               // bf16 1.0
  const bf16x8 vones = { one_bf, one_bf, one_bf, one_bf, one_bf, one_bf, one_bf, one_bf };

  f32x4 oacc[2][8] = {};
  f32x4 osum[2] = {};                               // row-sum of P (softmax denom), via MFMA

  {
    const u16* kg = Kbase + (size_t)m_beg * CCH;
    const u16* vg = Vbase + m_beg;
    #pragma unroll
    for (int j = 0; j < 4; ++j) {
      gl_lds16(kg + kgo[j], (u16*)lds + (j * 256 + t) * 8);
      gl_lds16(vg + vgo[j], (u16*)(lds + 32768) + (j * 256 + t) * 8);
    }
  }
  asm volatile("s_waitcnt vmcnt(0)" ::: "memory");
  __syncthreads();

  const int NT = KVCHUNK / 64;                      // 32 (even)

#define FLASH_BODY(CUR, M0, DOSTAGE)                                                   \
  {                                                                                    \
    if (DOSTAGE) {                                                                     \
      const u16* kg = Kbase + (size_t)((M0) + 64) * CCH;                               \
      const u16* vg = Vbase + ((M0) + 64);                                             \
      _Pragma("unroll")                                                                \
      for (int j = 0; j < 4; ++j) {                                                    \
        gl_lds16(kg + kgo[j], (u16*)(lds + ((CUR) ^ 1) * 16384) + (j * 256 + t) * 8);  \
        gl_lds16(vg + vgo[j], (u16*)(lds + 32768 + ((CUR) ^ 1) * 16384) + (j * 256 + t) * 8); \
      }                                                                                \
    }                                                                                  \
    f32x4 S[2][4] = {};                                                                \
    __builtin_amdgcn_s_setprio(1);                                                     \
    _Pragma("unroll")                                                                  \
    for (int kk = 0; kk < 4; ++kk)                                                     \
      _Pragma("unroll")                                                                \
      for (int mm = 0; mm < 4; ++mm) {                                                 \
        bf16x8 kf = *(const bf16x8*)(lds + kbase[kk] + mm * 4096 + (CUR) * 16384);     \
        S[0][mm] = MFMA16(kf, qf[0][kk], S[0][mm]);                                    \
        S[1][mm] = MFMA16(kf, qf[1][kk], S[1][mm]);                                    \
      }                                                                                \
    __builtin_amdgcn_s_setprio(0);                                                     \
    u32 pk[2][4][2];                                                                   \
    _Pragma("unroll")                                                                  \
    for (int mi = 0; mi < 2; ++mi) {                                                   \
      _Pragma("unroll")                                                                \
      for (int mm = 0; mm < 4; ++mm) {                                                 \
        f32x4 p;                                                                       \
        _Pragma("unroll")                                                              \
        for (int r = 0; r < 4; ++r) p[r] = exp2f(S[mi][mm][r]);                        \
        asm("v_cvt_pk_bf16_f32 %0, %1, %2" : "=v"(pk[mi][mm][0]) : "v"(p[0]), "v"(p[1])); \
        asm("v_cvt_pk_bf16_f32 %0, %1, %2" : "=v"(pk[mi][mm][1]) : "v"(p[2]), "v"(p[3])); \
      }                                                                                \
    }                                                                                  \
    bf16x8 pa[2][2];                                                                   \
    _Pragma("unroll")                                                                  \
    for (int mi = 0; mi < 2; ++mi)                                                     \
      _Pragma("unroll")                                                                \
      for (int ks = 0; ks < 2; ++ks) {                                                 \
        u32 a0 = pk[mi][2 * ks][0], a1 = pk[mi][2 * ks][1];                            \
        u32 b0 = pk[mi][2 * ks + 1][0], b1 = pk[mi][2 * ks + 1][1];                    \
        asm("v_permlane16_swap_b32 %0, %1" : "+v"(a0), "+v"(b0));                      \
        asm("v_permlane16_swap_b32 %0, %1" : "+v"(a1), "+v"(b1));                      \
        u32x4 w = { a0, a1, b0, b1 };                                                  \
        pa[mi][ks] = __builtin_bit_cast(bf16x8, w);                                    \
      }                                                                                \
    __builtin_amdgcn_s_setprio(1);                                                     \
    _Pragma("unroll")                                                                  \
    for (int ks = 0; ks < 2; ++ks) {                                                   \
      osum[0] = MFMA16(pa[0][ks], vones, osum[0]);                                     \
      osum[1] = MFMA16(pa[1][ks], vones, osum[1]);                                     \
      _Pragma("unroll")                                                                \
      for (int cc = 0; cc < 8; ++cc) {                                                 \
        bf16x8 vf = *(const bf16x8*)(lds + vbase[ks] + cc * 2048 + (CUR) * 16384);     \
        oacc[0][cc] = MFMA16(pa[0][ks], vf, oacc[0][cc]);                              \
        oacc[1][cc] = MFMA16(pa[1][ks], vf, oacc[1][cc]);                              \
      }                                                                                \
    }                                                                                  \
    __builtin_amdgcn_s_setprio(0);                                                     \
    asm volatile("s_waitcnt vmcnt(0)" ::: "memory");                                   \
    __syncthreads();                                                                   \
  }

  for (int it = 0; it < NT; it += 2) {
    FLASH_BODY(0, m_beg + it * 64, true)                    // NT even: it+1 < NT always
    FLASH_BODY(1, m_beg + it * 64 + 64, (it + 2 < NT))
  }
#undef FLASH_BODY

  // ---- epilogue: raw partial O + denominator l ----
  #pragma unroll
  for (int mi = 0; mi < 2; ++mi)
    #pragma unroll
    for (int cc = 0; cc < 8; ++cc)
      #pragma unroll
      for (int r = 0; r < 4; ++r)
        Ob[(size_t)(mi * 16 + lq * 4 + r) * HC + cc * 16 + l16] = f2b(oacc[mi][cc][r]);
  if (l16 == 0) {
    #pragma unroll
    for (int mi = 0; mi < 2; ++mi)
      #pragma unroll
      for (int r = 0; r < 4; ++r)
        mlp[mlR0 + mi * 16 + lq * 4 + r] = osum[mi][r];
  }
}

// ---------- 6. split merge (2 splits, l-only weights) ----------
__global__ void merge_k(const u16* __restrict__ s0, const u16* __restrict__ s1,
                        const float* __restrict__ ml, u16* __restrict__ Ot) {
  int t = threadIdx.x;
  int R = blockIdx.x * 32 + (t >> 3);        // row 0..32767 ([b][h][q])
  int ch = (t & 7) * 16;
  float L = ml[R] + ml[32768 + R];
  float inv = 1.f / L;
  float acc[16] = {};
  const u16* sp[2] = { s0, s1 };
  #pragma unroll
  for (int s = 0; s < 2; ++s) {
    const bf16x8* p = (const bf16x8*)(sp[s] + (size_t)R * HC + ch);
    #pragma unroll
    for (int j = 0; j < 2; ++j) {
      bf16x8 v = p[j];
      #pragma unroll
      for (int e = 0; e < 8; ++e) acc[j * 8 + e] += b2f((u16)v[e]);
    }
  }
  int b = R >> 14, h = (R >> 12) & 3, q = R & 4095;
  u16* o = Ot + ((size_t)((b << 12) + q) * CCH) + h * HC + ch;
  #pragma unroll
  for (int j = 0; j < 4; ++j) {
    u16x4 o4 = { f2b(acc[j*4] * inv), f2b(acc[j*4+1] * inv),
                 f2b(acc[j*4+2] * inv), f2b(acc[j*4+3] * inv) };
    *(u16x4*)(o + j * 4) = o4;
  }
}

// ---------- launch ----------
extern "C" void kernel_launch(void* const* d_in, const int* in_sizes, int n_in,
                              void* d_out, int out_size, void* d_ws, size_t ws_size,
                              hipStream_t stream) {
  const float* x   = (const float*)d_in[0];
  const float* gns = (const float*)d_in[1];
  const float* gnb = (const float*)d_in[2];
  const float* wq  = (const float*)d_in[3];
  const float* bq  = (const float*)d_in[4];
  const float* wk  = (const float*)d_in[5];
  const float* bk  = (const float*)d_in[6];
  const float* wv  = (const float*)d_in[7];
  const float* bv  = (const float*)d_in[8];
  const float* wo  = (const float*)d_in[9];
  const float* bo  = (const float*)d_in[10];
  float* out = (float*)d_out;
  char* ws = (char*)d_ws;

  u16*   wb    = (u16*)ws;                          // 4 x 512x512 bf16 = 2 MiB ([wq;wk] contiguous)
  u16*   Ht    = (u16*)(ws + (size_t)( 2u << 20));  // [2][4096][512] (dead after V gemm)
  u16*   Qt    = (u16*)(ws + (size_t)(10u << 20));
  u16*   Kt    = (u16*)(ws + (size_t)(18u << 20));
  u16*   Vc    = (u16*)(ws + (size_t)(26u << 20));  // [2][512][4096]
  u16*   Ot    = (u16*)(ws + (size_t)(34u << 20));
  float* mlb   = (float*)(ws + (size_t)(42u << 20)); // [2][32768] f32 = 256 KiB
  float* stats = (float*)(ws + (size_t)(43u << 20)); // pstats [256][2]
  // partial-O slabs in dead/overwritten-later space:
  u16*   sl0   = Ht;                                 // Ht dead after V gemm
  u16*   sl1   = (u16*)d_out;                        // consumed by merge before final gemm writes

  wconv_k   <<<dim3(256, 4, 1), 256, 0, stream>>>(wq, wk, wv, wo, wb);
  gn_stats_k<<<dim3(256, 1, 1), 256, 0, stream>>>(x, stats);
  gn_norm_k <<<dim3(8, 64, 2),  256, 0, stream>>>(x, gns, gnb, stats, Ht);
  gemm_nt<3><<<dim3(64, 8, 1),  256, 0, stream>>>(Ht, wb, bq, bk, Qt, Kt, nullptr, nullptr,
                                                  QK_SCALE * LOG2E);
  gemm_nt<1><<<dim3(4, 32, 2),  256, 0, stream>>>(wb + 2u * 262144u, Ht, bv, nullptr, Vc, nullptr,
                                                  nullptr, nullptr, 1.0f);
  flash_k   <<<dim3(512, 1, 1), 256, 0, stream>>>(Qt, Kt, Vc, sl0, sl1, mlb);
  merge_k   <<<dim3(1024, 1, 1),256, 0, stream>>>(sl0, sl1, mlb, Ot);
  gemm_nt<2><<<dim3(4, 32, 2),  256, 0, stream>>>(wb + 3u * 262144u, Ot, bo, nullptr, nullptr,
                                                  nullptr, out, x, 1.0f);
}

// Round 13
// 153.539 us; speedup vs baseline: 2.9275x; 1.0174x over previous
//
#include <hip/hip_runtime.h>

// ---------- types ----------
typedef float    f32x4 __attribute__((ext_vector_type(4)));
typedef short    bf16x8 __attribute__((ext_vector_type(8)));
typedef unsigned short u16;
typedef u16      u16x4 __attribute__((ext_vector_type(4)));
typedef unsigned u32;
typedef u32      u32x4 __attribute__((ext_vector_type(4)));

#define MFMA16(a, b, c) __builtin_amdgcn_mfma_f32_16x16x32_bf16((a), (b), (c), 0, 0, 0)

#define CCH 512          // channels
#define NPIX 4096        // 64*64 pixels
#define NHEAD 4
#define HC 128           // head channels
#define NSPLIT 2         // flash-decoding KV splits
#define KVCHUNK (NPIX / NSPLIT)
#define QK_SCALE 0.04419417382415922f   // 1/sqrt(512)  (repo quirk: full C)
#define LOG2E 1.4426950408889634f

__device__ __forceinline__ u16 f2b(float f) {
  unsigned u = __builtin_bit_cast(unsigned, f);
  u += 0x7FFFu + ((u >> 16) & 1u);      // RNE
  return (u16)(u >> 16);
}
__device__ __forceinline__ float b2f(u16 b) {
  return __builtin_bit_cast(float, ((unsigned)b) << 16);
}

__device__ __forceinline__ void gl_lds16(const u16* g, u16* l) {
  __builtin_amdgcn_global_load_lds((const __attribute__((address_space(1))) void*)g,
                                   (__attribute__((address_space(3))) void*)l, 16, 0, 0);
}

// ---------- 1. fused: weights fp32->bf16 (blocks 0..1023) + GN partial stats (1024..1279) ----------
__global__ void prep_k(const float* __restrict__ w0, const float* __restrict__ w1,
                       const float* __restrict__ w2, const float* __restrict__ w3,
                       u16* __restrict__ dst,
                       const float* __restrict__ x, float* __restrict__ pstats) {
  int blk = blockIdx.x, t = threadIdx.x;
  if (blk < 1024) {                          // ---- weight convert ----
    int m = blk >> 8;
    const float* src = (m == 0) ? w0 : (m == 1) ? w1 : (m == 2) ? w2 : w3;
    int i = ((blk & 255) * 256 + t) * 4;
    f32x4 v = *(const f32x4*)(src + i);
    u16x4 o = { f2b(v[0]), f2b(v[1]), f2b(v[2]), f2b(v[3]) };
    *(u16x4*)(dst + (size_t)m * (CCH * CCH) + i) = o;
    return;
  }
  // ---- GroupNorm partial statistics: 4 chunks per (b, group) ----
  int sblk = blk - 1024;                     // 0..255 = bg*4 + chunk
  const f32x4* p = (const f32x4*)(x + (size_t)sblk * 16384);
  int wv = t >> 6, l = t & 63;
  float s = 0.f, ss = 0.f;
  for (int i = t; i < 4096; i += 256) {
    f32x4 v = p[i];
    s  += v[0] + v[1] + v[2] + v[3];
    ss += v[0]*v[0] + v[1]*v[1] + v[2]*v[2] + v[3]*v[3];
  }
  #pragma unroll
  for (int d = 32; d; d >>= 1) { s += __shfl_down(s, d, 64); ss += __shfl_down(ss, d, 64); }
  __shared__ float red[8];
  if (l == 0) { red[wv*2] = s; red[wv*2+1] = ss; }
  __syncthreads();
  if (t == 0) {
    pstats[sblk*2]   = red[0] + red[2] + red[4] + red[6];
    pstats[sblk*2+1] = red[1] + red[3] + red[5] + red[7];
  }
}

// ---------- 3. GN apply + transpose ----------
__global__ void gn_norm_k(const float* __restrict__ x, const float* __restrict__ gns,
                          const float* __restrict__ gnb, const float* __restrict__ pstats,
                          u16* __restrict__ Ht) {
  int t = threadIdx.x;
  int ct = blockIdx.x * 64, nt = blockIdx.y * 64, b = blockIdx.z;
  int c0 = ct + (t & 15) * 4;
  int n0 = nt + (t >> 4) * 4;
  const float* xb = x + ((size_t)b * CCH + c0) * NPIX + n0;
  int g = b * 32 + (c0 >> 4);
  const f32x4* ps = (const f32x4*)(pstats + g * 8);
  f32x4 p0 = ps[0], p1 = ps[1];
  float s  = p0[0] + p0[2] + p1[0] + p1[2];
  float ss = p0[1] + p0[3] + p1[1] + p1[3];
  float mean = s * (1.f/65536.f);
  float var  = ss * (1.f/65536.f) - mean*mean;
  float rstd = rsqrtf(var + 1e-6f);
  f32x4 rows[4];
  #pragma unroll
  for (int j = 0; j < 4; ++j) {
    f32x4 v = *(const f32x4*)(xb + (size_t)j * NPIX);
    float a  = rstd * gns[c0 + j];
    float bb = gnb[c0 + j] - mean * a;
    rows[j] = v * a + bb;
  }
  #pragma unroll
  for (int i = 0; i < 4; ++i) {
    u16x4 o = { f2b(rows[0][i]), f2b(rows[1][i]), f2b(rows[2][i]), f2b(rows[3][i]) };
    *(u16x4*)(Ht + ((size_t)b * NPIX + n0 + i) * CCH + c0) = o;
  }
}

// ---------- 4. NT GEMM, 128x128 tiles, double-buffered K-loop (flash-style schedule) ----------
// MODE 1: A=W, B=Ht[z]           -> outb[z][row=o][col=pix], bias[row]
// MODE 2: A=Wo, B=Ot[z], resid=x -> outf[z][row=o][col=pix] fp32
// MODE 3: A=Ht flat [8192][512], B=[wq;wk] stacked [1024][512]
//         gcol<512 -> outb=Qt (alpha, bias) ; else outb2=Kt (bias2)
template<int MODE>
__global__ __launch_bounds__(256) void gemm_nt(const u16* __restrict__ A,
                                               const u16* __restrict__ B,
                                               const float* __restrict__ bias,
                                               const float* __restrict__ bias2,
                                               u16* __restrict__ outb,
                                               u16* __restrict__ outb2,
                                               float* __restrict__ outf,
                                               const float* __restrict__ resid,
                                               float alpha) {
  __shared__ __align__(16) u16 As[2][128 * 32];
  __shared__ __align__(16) u16 Bs[2][128 * 32];
  const int t = threadIdx.x, l = t & 63, wv = t >> 6;
  const int l16 = l & 15, lq = l >> 4;
  const int mt = blockIdx.x * 128, nt = blockIdx.y * 128, z = blockIdx.z;
  const u16* Ap = A + (size_t)mt * CCH;
  const u16* Bp = (MODE == 3) ? (B + (size_t)nt * CCH)
                              : (B + ((size_t)z * NPIX + nt) * CCH);
  const int wm = (wv >> 1) * 64, wn = (wv & 1) * 64;
  f32x4 acc[4][4] = {};

  // ---- prologue: stage k=0 into buf 0 ----
  #pragma unroll
  for (int j = 0; j < 2; ++j) {
    int idx = t + j * 256;
    int row = idx >> 2, kc = (idx & 3) * 8;
    gl_lds16(Ap + (size_t)row * CCH + kc, &As[0][0] + idx * 8);
    gl_lds16(Bp + (size_t)row * CCH + kc, &Bs[0][0] + idx * 8);
  }
  asm volatile("s_waitcnt vmcnt(0)" ::: "memory");
  __syncthreads();

#define GEMM_BODY(CUR, K0, DOSTAGE)                                                   \
  {                                                                                   \
    if (DOSTAGE) {                                                                    \
      _Pragma("unroll")                                                               \
      for (int j = 0; j < 2; ++j) {                                                   \
        int idx = t + j * 256;                                                        \
        int row = idx >> 2, kc = (idx & 3) * 8;                                       \
        gl_lds16(Ap + (size_t)row * CCH + (K0) + 32 + kc, &As[(CUR) ^ 1][0] + idx * 8); \
        gl_lds16(Bp + (size_t)row * CCH + (K0) + 32 + kc, &Bs[(CUR) ^ 1][0] + idx * 8); \
      }                                                                               \
    }                                                                                 \
    bf16x8 af[4], bfr[4];                                                             \
    _Pragma("unroll")                                                                 \
    for (int i = 0; i < 4; ++i) {                                                     \
      af[i]  = *(const bf16x8*)(&As[CUR][0] + (wm + i * 16 + l16) * 32 + lq * 8);     \
      bfr[i] = *(const bf16x8*)(&Bs[CUR][0] + (wn + i * 16 + l16) * 32 + lq * 8);     \
    }                                                                                 \
    _Pragma("unroll")                                                                 \
    for (int mi = 0; mi < 4; ++mi)                                                    \
      _Pragma("unroll")                                                               \
      for (int ni = 0; ni < 4; ++ni)                                                  \
        acc[mi][ni] = MFMA16(af[mi], bfr[ni], acc[mi][ni]);                           \
    asm volatile("s_waitcnt vmcnt(0)" ::: "memory");                                  \
    __syncthreads();                                                                  \
  }

  for (int k0 = 0; k0 < CCH; k0 += 64) {
    GEMM_BODY(0, k0, true)                       // stages k0+32 (<= 480, always valid)
    GEMM_BODY(1, k0 + 32, (k0 + 64 < CCH))       // stages k0+64 unless last
  }
#undef GEMM_BODY

  #pragma unroll
  for (int mi = 0; mi < 4; ++mi)
    #pragma unroll
    for (int ni = 0; ni < 4; ++ni)
      #pragma unroll
      for (int r = 0; r < 4; ++r) {
        int grow = mt + wm + mi * 16 + lq * 4 + r;
        int gcol = nt + wn + ni * 16 + l16;
        float v = acc[mi][ni][r];
        if (MODE == 1) {
          outb[((size_t)z * CCH + grow) * NPIX + gcol] = f2b(v + bias[grow]);
        } else if (MODE == 2) {
          size_t off = ((size_t)z * CCH + grow) * NPIX + gcol;
          outf[off] = v + bias[grow] + resid[off];
        } else {  // MODE 3
          if (gcol < 512)
            outb[(size_t)grow * CCH + gcol] = f2b((v + bias[gcol]) * alpha);
          else
            outb2[(size_t)grow * CCH + (gcol - 512)] = f2b(v + bias2[gcol - 512]);
        }
      }
}

// ---------- 5. Flash attention (proven R6 structure — unchanged) ----------
// No-max softmax: S (log2-domain, scale folded in Q) is bounded (86-sigma margin),
// so P = exp2(S) directly; denominator l = sum_k P via ones-B MFMA on matrix pipe.
// K+V double-buffered in 64KB LDS; one stage + one vmcnt(0)+syncthreads per tile.
__global__ __launch_bounds__(256, 2) void flash_k(const u16* __restrict__ Qt,
                                                  const u16* __restrict__ Kt,
                                                  const u16* __restrict__ Vc,
                                                  u16* __restrict__ sl0, u16* __restrict__ sl1,
                                                  float* __restrict__ mlp) {
  __shared__ __align__(16) char lds[65536];
  const int t = threadIdx.x, wv = t >> 6, l = t & 63;
  const int l16 = l & 15, lq = l >> 4;
  const int orig = blockIdx.x;
  const int gid = (orig & 7) * 64 + (orig >> 3);     // XCD-chunked remap (512%8==0)
  const int qx = gid & 31, grp = gid >> 5;
  const int hd = grp & 3, b = (grp >> 2) & 1, s = grp >> 3;
  const int qt0 = qx * 128 + wv * 32;

  const u16* Q = Qt + ((size_t)b * NPIX + qt0) * CCH + hd * HC;
  const u16* Kbase = Kt + (size_t)b * NPIX * CCH + hd * HC;          // [key][CCH]
  const u16* Vbase = Vc + (size_t)b * CCH * NPIX + (size_t)hd * HC * NPIX; // [ch][NPIX]
  u16* slab = (s == 0) ? sl0 : sl1;
  u16* Ob = slab + ((size_t)(b * NHEAD + hd) * NPIX + qt0) * HC;
  size_t mlR0 = (size_t)s * 32768 + (size_t)(b * NHEAD + hd) * NPIX + qt0;

  bf16x8 qf[2][4];
  #pragma unroll
  for (int mi = 0; mi < 2; ++mi)
    #pragma unroll
    for (int kk = 0; kk < 4; ++kk)
      qf[mi][kk] = *(const bf16x8*)(Q + (size_t)(mi * 16 + l16) * CCH + kk * 32 + lq * 8);

  const int m_beg = s * KVCHUNK;
  const int sw = (l16 & 7) << 4;                    // per-lane swizzle nibble
  const int vb2 = (lq & 1) * 32 + (lq >> 1) * 16;   // permuted key-base (permlane order)

  int kbase[4], vbase[2];
  #pragma unroll
  for (int kk = 0; kk < 4; ++kk) kbase[kk] = l16 * 256 + ((kk * 64 + lq * 16) ^ sw);
  #pragma unroll
  for (int ks = 0; ks < 2; ++ks) vbase[ks] = 32768 + l16 * 128 + ((ks * 64 + vb2) ^ sw);

  u32 kgo[4], vgo[4];
  #pragma unroll
  for (int j = 0; j < 4; ++j) {
    int g = j * 256 + t;
    { int row = g >> 4, src = ((g & 15) << 4) ^ ((row & 7) << 4);
      kgo[j] = (u32)row * CCH + (src >> 1); }
    { int row = g >> 3, src = ((g & 7) << 4) ^ ((row & 7) << 4);
      vgo[j] = (u32)row * NPIX + (src >> 1); }
  }

  const short one_bf = (short)0x3F80;               // bf16 1.0
  const bf16x8 vones = { one_bf, one_bf, one_bf, one_bf, one_bf, one_bf, one_bf, one_bf };

  f32x4 oacc[2][8] = {};
  f32x4 osum[2] = {};                               // row-sum of P (softmax denom), via MFMA

  {
    const u16* kg = Kbase + (size_t)m_beg * CCH;
    const u16* vg = Vbase + m_beg;
    #pragma unroll
    for (int j = 0; j < 4; ++j) {
      gl_lds16(kg + kgo[j], (u16*)lds + (j * 256 + t) * 8);
      gl_lds16(vg + vgo[j], (u16*)(lds + 32768) + (j * 256 + t) * 8);
    }
  }
  asm volatile("s_waitcnt vmcnt(0)" ::: "memory");
  __syncthreads();

  const int NT = KVCHUNK / 64;                      // 32 (even)

#define FLASH_BODY(CUR, M0, DOSTAGE)                                                   \
  {                                                                                    \
    if (DOSTAGE) {                                                                     \
      const u16* kg = Kbase + (size_t)((M0) + 64) * CCH;                               \
      const u16* vg = Vbase + ((M0) + 64);                                             \
      _Pragma("unroll")                                                                \
      for (int j = 0; j < 4; ++j) {                                                    \
        gl_lds16(kg + kgo[j], (u16*)(lds + ((CUR) ^ 1) * 16384) + (j * 256 + t) * 8);  \
        gl_lds16(vg + vgo[j], (u16*)(lds + 32768 + ((CUR) ^ 1) * 16384) + (j * 256 + t) * 8); \
      }                                                                                \
    }                                                                                  \
    f32x4 S[2][4] = {};                                                                \
    __builtin_amdgcn_s_setprio(1);                                                     \
    _Pragma("unroll")                                                                  \
    for (int kk = 0; kk < 4; ++kk)                                                     \
      _Pragma("unroll")                                                                \
      for (int mm = 0; mm < 4; ++mm) {                                                 \
        bf16x8 kf = *(const bf16x8*)(lds + kbase[kk] + mm * 4096 + (CUR) * 16384);     \
        S[0][mm] = MFMA16(kf, qf[0][kk], S[0][mm]);                                    \
        S[1][mm] = MFMA16(kf, qf[1][kk], S[1][mm]);                                    \
      }                                                                                \
    __builtin_amdgcn_s_setprio(0);                                                     \
    u32 pk[2][4][2];                                                                   \
    _Pragma("unroll")                                                                  \
    for (int mi = 0; mi < 2; ++mi) {                                                   \
      _Pragma("unroll")                                                                \
      for (int mm = 0; mm < 4; ++mm) {                                                 \
        f32x4 p;                                                                       \
        _Pragma("unroll")                                                              \
        for (int r = 0; r < 4; ++r) p[r] = exp2f(S[mi][mm][r]);                        \
        asm("v_cvt_pk_bf16_f32 %0, %1, %2" : "=v"(pk[mi][mm][0]) : "v"(p[0]), "v"(p[1])); \
        asm("v_cvt_pk_bf16_f32 %0, %1, %2" : "=v"(pk[mi][mm][1]) : "v"(p[2]), "v"(p[3])); \
      }                                                                                \
    }                                                                                  \
    bf16x8 pa[2][2];                                                                   \
    _Pragma("unroll")                                                                  \
    for (int mi = 0; mi < 2; ++mi)                                                     \
      _Pragma("unroll")                                                                \
      for (int ks = 0; ks < 2; ++ks) {                                                 \
        u32 a0 = pk[mi][2 * ks][0], a1 = pk[mi][2 * ks][1];                            \
        u32 b0 = pk[mi][2 * ks + 1][0], b1 = pk[mi][2 * ks + 1][1];                    \
        asm("v_permlane16_swap_b32 %0, %1" : "+v"(a0), "+v"(b0));                      \
        asm("v_permlane16_swap_b32 %0, %1" : "+v"(a1), "+v"(b1));                      \
        u32x4 w = { a0, a1, b0, b1 };                                                  \
        pa[mi][ks] = __builtin_bit_cast(bf16x8, w);                                    \
      }                                                                                \
    __builtin_amdgcn_s_setprio(1);                                                     \
    _Pragma("unroll")                                                                  \
    for (int ks = 0; ks < 2; ++ks) {                                                   \
      osum[0] = MFMA16(pa[0][ks], vones, osum[0]);                                     \
      osum[1] = MFMA16(pa[1][ks], vones, osum[1]);                                     \
      _Pragma("unroll")                                                                \
      for (int cc = 0; cc < 8; ++cc) {                                                 \
        bf16x8 vf = *(const bf16x8*)(lds + vbase[ks] + cc * 2048 + (CUR) * 16384);     \
        oacc[0][cc] = MFMA16(pa[0][ks], vf, oacc[0][cc]);                              \
        oacc[1][cc] = MFMA16(pa[1][ks], vf, oacc[1][cc]);                              \
      }                                                                                \
    }                                                                                  \
    __builtin_amdgcn_s_setprio(0);                                                     \
    asm volatile("s_waitcnt vmcnt(0)" ::: "memory");                                   \
    __syncthreads();                                                                   \
  }

  for (int it = 0; it < NT; it += 2) {
    FLASH_BODY(0, m_beg + it * 64, true)                    // NT even: it+1 < NT always
    FLASH_BODY(1, m_beg + it * 64 + 64, (it + 2 < NT))
  }
#undef FLASH_BODY

  // ---- epilogue: raw partial O + denominator l ----
  #pragma unroll
  for (int mi = 0; mi < 2; ++mi)
    #pragma unroll
    for (int cc = 0; cc < 8; ++cc)
      #pragma unroll
      for (int r = 0; r < 4; ++r)
        Ob[(size_t)(mi * 16 + lq * 4 + r) * HC + cc * 16 + l16] = f2b(oacc[mi][cc][r]);
  if (l16 == 0) {
    #pragma unroll
    for (int mi = 0; mi < 2; ++mi)
      #pragma unroll
      for (int r = 0; r < 4; ++r)
        mlp[mlR0 + mi * 16 + lq * 4 + r] = osum[mi][r];
  }
}

// ---------- 6. split merge (2 splits, l-only weights) ----------
__global__ void merge_k(const u16* __restrict__ s0, const u16* __restrict__ s1,
                        const float* __restrict__ ml, u16* __restrict__ Ot) {
  int t = threadIdx.x;
  int R = blockIdx.x * 32 + (t >> 3);        // row 0..32767 ([b][h][q])
  int ch = (t & 7) * 16;
  float L = ml[R] + ml[32768 + R];
  float inv = 1.f / L;
  float acc[16] = {};
  const u16* sp[2] = { s0, s1 };
  #pragma unroll
  for (int s = 0; s < 2; ++s) {
    const bf16x8* p = (const bf16x8*)(sp[s] + (size_t)R * HC + ch);
    #pragma unroll
    for (int j = 0; j < 2; ++j) {
      bf16x8 v = p[j];
      #pragma unroll
      for (int e = 0; e < 8; ++e) acc[j * 8 + e] += b2f((u16)v[e]);
    }
  }
  int b = R >> 14, h = (R >> 12) & 3, q = R & 4095;
  u16* o = Ot + ((size_t)((b << 12) + q) * CCH) + h * HC + ch;
  #pragma unroll
  for (int j = 0; j < 4; ++j) {
    u16x4 o4 = { f2b(acc[j*4] * inv), f2b(acc[j*4+1] * inv),
                 f2b(acc[j*4+2] * inv), f2b(acc[j*4+3] * inv) };
    *(u16x4*)(o + j * 4) = o4;
  }
}

// ---------- launch ----------
extern "C" void kernel_launch(void* const* d_in, const int* in_sizes, int n_in,
                              void* d_out, int out_size, void* d_ws, size_t ws_size,
                              hipStream_t stream) {
  const float* x   = (const float*)d_in[0];
  const float* gns = (const float*)d_in[1];
  const float* gnb = (const float*)d_in[2];
  const float* wq  = (const float*)d_in[3];
  const float* bq  = (const float*)d_in[4];
  const float* wk  = (const float*)d_in[5];
  const float* bk  = (const float*)d_in[6];
  const float* wv  = (const float*)d_in[7];
  const float* bv  = (const float*)d_in[8];
  const float* wo  = (const float*)d_in[9];
  const float* bo  = (const float*)d_in[10];
  float* out = (float*)d_out;
  char* ws = (char*)d_ws;

  u16*   wb    = (u16*)ws;                          // 4 x 512x512 bf16 = 2 MiB ([wq;wk] contiguous)
  u16*   Ht    = (u16*)(ws + (size_t)( 2u << 20));  // [2][4096][512] (dead after V gemm)
  u16*   Qt    = (u16*)(ws + (size_t)(10u << 20));
  u16*   Kt    = (u16*)(ws + (size_t)(18u << 20));
  u16*   Vc    = (u16*)(ws + (size_t)(26u << 20));  // [2][512][4096]
  u16*   Ot    = (u16*)(ws + (size_t)(34u << 20));
  float* mlb   = (float*)(ws + (size_t)(42u << 20)); // [2][32768] f32 = 256 KiB
  float* stats = (float*)(ws + (size_t)(43u << 20)); // pstats [256][2]
  // partial-O slabs in dead/overwritten-later space:
  u16*   sl0   = Ht;                                 // Ht dead after V gemm
  u16*   sl1   = (u16*)d_out;                        // consumed by merge before final gemm writes

  prep_k    <<<dim3(1280, 1, 1), 256, 0, stream>>>(wq, wk, wv, wo, wb, x, stats);
  gn_norm_k <<<dim3(8, 64, 2),  256, 0, stream>>>(x, gns, gnb, stats, Ht);
  gemm_nt<3><<<dim3(64, 8, 1),  256, 0, stream>>>(Ht, wb, bq, bk, Qt, Kt, nullptr, nullptr,
                                                  QK_SCALE * LOG2E);
  gemm_nt<1><<<dim3(4, 32, 2),  256, 0, stream>>>(wb + 2u * 262144u, Ht, bv, nullptr, Vc, nullptr,
                                                  nullptr, nullptr, 1.0f);
  flash_k   <<<dim3(512, 1, 1), 256, 0, stream>>>(Qt, Kt, Vc, sl0, sl1, mlb);
  merge_k   <<<dim3(1024, 1, 1),256, 0, stream>>>(sl0, sl1, mlb, Ot);
  gemm_nt<2><<<dim3(4, 32, 2),  256, 0, stream>>>(wb + 3u * 262144u, Ot, bo, nullptr, nullptr,
                                                  nullptr, out, x, 1.0f);
}

// Round 14
// 147.499 us; speedup vs baseline: 3.0474x; 1.0410x over previous
//
#include <hip/hip_runtime.h>

// ---------- types ----------
typedef float    f32x4 __attribute__((ext_vector_type(4)));
typedef short    bf16x8 __attribute__((ext_vector_type(8)));
typedef unsigned short u16;
typedef u16      u16x4 __attribute__((ext_vector_type(4)));
typedef unsigned u32;
typedef u32      u32x4 __attribute__((ext_vector_type(4)));

#define MFMA16(a, b, c) __builtin_amdgcn_mfma_f32_16x16x32_bf16((a), (b), (c), 0, 0, 0)

#define CCH 512          // channels
#define NPIX 4096        // 64*64 pixels
#define NHEAD 4
#define HC 128           // head channels
#define NSPLIT 2         // flash-decoding KV splits
#define KVCHUNK (NPIX / NSPLIT)
#define QK_SCALE 0.04419417382415922f   // 1/sqrt(512)  (repo quirk: full C)
#define LOG2E 1.4426950408889634f

__device__ __forceinline__ u16 f2b(float f) {
  unsigned u = __builtin_bit_cast(unsigned, f);
  u += 0x7FFFu + ((u >> 16) & 1u);      // RNE
  return (u16)(u >> 16);
}
__device__ __forceinline__ float b2f(u16 b) {
  return __builtin_bit_cast(float, ((unsigned)b) << 16);
}

__device__ __forceinline__ void gl_lds16(const u16* g, u16* l) {
  __builtin_amdgcn_global_load_lds((const __attribute__((address_space(1))) void*)g,
                                   (__attribute__((address_space(3))) void*)l, 16, 0, 0);
}

// ---------- 1. fused: weights fp32->bf16 (blocks 0..1023) + GN partial stats (1024..1279) ----------
__global__ void prep_k(const float* __restrict__ w0, const float* __restrict__ w1,
                       const float* __restrict__ w2, const float* __restrict__ w3,
                       u16* __restrict__ dst,
                       const float* __restrict__ x, float* __restrict__ pstats) {
  int blk = blockIdx.x, t = threadIdx.x;
  if (blk < 1024) {                          // ---- weight convert ----
    int m = blk >> 8;
    const float* src = (m == 0) ? w0 : (m == 1) ? w1 : (m == 2) ? w2 : w3;
    int i = ((blk & 255) * 256 + t) * 4;
    f32x4 v = *(const f32x4*)(src + i);
    u16x4 o = { f2b(v[0]), f2b(v[1]), f2b(v[2]), f2b(v[3]) };
    *(u16x4*)(dst + (size_t)m * (CCH * CCH) + i) = o;
    return;
  }
  // ---- GroupNorm partial statistics: 4 chunks per (b, group) ----
  int sblk = blk - 1024;                     // 0..255 = bg*4 + chunk
  const f32x4* p = (const f32x4*)(x + (size_t)sblk * 16384);
  int wv = t >> 6, l = t & 63;
  float s = 0.f, ss = 0.f;
  for (int i = t; i < 4096; i += 256) {
    f32x4 v = p[i];
    s  += v[0] + v[1] + v[2] + v[3];
    ss += v[0]*v[0] + v[1]*v[1] + v[2]*v[2] + v[3]*v[3];
  }
  #pragma unroll
  for (int d = 32; d; d >>= 1) { s += __shfl_down(s, d, 64); ss += __shfl_down(ss, d, 64); }
  __shared__ float red[8];
  if (l == 0) { red[wv*2] = s; red[wv*2+1] = ss; }
  __syncthreads();
  if (t == 0) {
    pstats[sblk*2]   = red[0] + red[2] + red[4] + red[6];
    pstats[sblk*2+1] = red[1] + red[3] + red[5] + red[7];
  }
}

// ---------- 2. GN apply + transpose ----------
__global__ void gn_norm_k(const float* __restrict__ x, const float* __restrict__ gns,
                          const float* __restrict__ gnb, const float* __restrict__ pstats,
                          u16* __restrict__ Ht) {
  int t = threadIdx.x;
  int ct = blockIdx.x * 64, nt = blockIdx.y * 64, b = blockIdx.z;
  int c0 = ct + (t & 15) * 4;
  int n0 = nt + (t >> 4) * 4;
  const float* xb = x + ((size_t)b * CCH + c0) * NPIX + n0;
  int g = b * 32 + (c0 >> 4);
  const f32x4* ps = (const f32x4*)(pstats + g * 8);
  f32x4 p0 = ps[0], p1 = ps[1];
  float s  = p0[0] + p0[2] + p1[0] + p1[2];
  float ss = p0[1] + p0[3] + p1[1] + p1[3];
  float mean = s * (1.f/65536.f);
  float var  = ss * (1.f/65536.f) - mean*mean;
  float rstd = rsqrtf(var + 1e-6f);
  f32x4 rows[4];
  #pragma unroll
  for (int j = 0; j < 4; ++j) {
    f32x4 v = *(const f32x4*)(xb + (size_t)j * NPIX);
    float a  = rstd * gns[c0 + j];
    float bb = gnb[c0 + j] - mean * a;
    rows[j] = v * a + bb;
  }
  #pragma unroll
  for (int i = 0; i < 4; ++i) {
    u16x4 o = { f2b(rows[0][i]), f2b(rows[1][i]), f2b(rows[2][i]), f2b(rows[3][i]) };
    *(u16x4*)(Ht + ((size_t)b * NPIX + n0 + i) * CCH + c0) = o;
  }
}

// ---------- 3. NT GEMM body, 128x128 tiles, double-buffered (proven R13 structure) ----------
// MODE 1: A=W, B=Ht[z]           -> outb[z][row=o][col=pix], bias[row]
// MODE 3: A=Ht flat [8192][512], B=[wq;wk] stacked [1024][512]
//         gcol<512 -> outb=Qt (alpha, bias) ; else outb2=Kt (bias2)
template<int MODE>
__device__ __forceinline__ void gemm_body(const u16* __restrict__ A,
                                          const u16* __restrict__ B,
                                          const float* __restrict__ bias,
                                          const float* __restrict__ bias2,
                                          u16* __restrict__ outb,
                                          u16* __restrict__ outb2,
                                          float alpha,
                                          int bx, int by, int z,
                                          u16* As, u16* Bs) {   // each [2][4096]
  const int t = threadIdx.x, l = t & 63, wv = t >> 6;
  const int l16 = l & 15, lq = l >> 4;
  const int mt = bx * 128, nt = by * 128;
  const u16* Ap = A + (size_t)mt * CCH;
  const u16* Bp = (MODE == 3) ? (B + (size_t)nt * CCH)
                              : (B + ((size_t)z * NPIX + nt) * CCH);
  const int wm = (wv >> 1) * 64, wn = (wv & 1) * 64;
  f32x4 acc[4][4] = {};

  // ---- prologue: stage k=0 into buf 0 ----
  #pragma unroll
  for (int j = 0; j < 2; ++j) {
    int idx = t + j * 256;
    int row = idx >> 2, kc = (idx & 3) * 8;
    gl_lds16(Ap + (size_t)row * CCH + kc, As + idx * 8);
    gl_lds16(Bp + (size_t)row * CCH + kc, Bs + idx * 8);
  }
  asm volatile("s_waitcnt vmcnt(0)" ::: "memory");
  __syncthreads();

#define GEMM_BODY(CUR, K0, DOSTAGE)                                                   \
  {                                                                                   \
    if (DOSTAGE) {                                                                    \
      _Pragma("unroll")                                                               \
      for (int j = 0; j < 2; ++j) {                                                   \
        int idx = t + j * 256;                                                        \
        int row = idx >> 2, kc = (idx & 3) * 8;                                       \
        gl_lds16(Ap + (size_t)row * CCH + (K0) + 32 + kc, As + ((CUR) ^ 1) * 4096 + idx * 8); \
        gl_lds16(Bp + (size_t)row * CCH + (K0) + 32 + kc, Bs + ((CUR) ^ 1) * 4096 + idx * 8); \
      }                                                                               \
    }                                                                                 \
    bf16x8 af[4], bfr[4];                                                             \
    _Pragma("unroll")                                                                 \
    for (int i = 0; i < 4; ++i) {                                                     \
      af[i]  = *(const bf16x8*)(As + (CUR) * 4096 + (wm + i * 16 + l16) * 32 + lq * 8); \
      bfr[i] = *(const bf16x8*)(Bs + (CUR) * 4096 + (wn + i * 16 + l16) * 32 + lq * 8); \
    }                                                                                 \
    _Pragma("unroll")                                                                 \
    for (int mi = 0; mi < 4; ++mi)                                                    \
      _Pragma("unroll")                                                               \
      for (int ni = 0; ni < 4; ++ni)                                                  \
        acc[mi][ni] = MFMA16(af[mi], bfr[ni], acc[mi][ni]);                           \
    asm volatile("s_waitcnt vmcnt(0)" ::: "memory");                                  \
    __syncthreads();                                                                  \
  }

  for (int k0 = 0; k0 < CCH; k0 += 64) {
    GEMM_BODY(0, k0, true)
    GEMM_BODY(1, k0 + 32, (k0 + 64 < CCH))
  }
#undef GEMM_BODY

  #pragma unroll
  for (int mi = 0; mi < 4; ++mi)
    #pragma unroll
    for (int ni = 0; ni < 4; ++ni)
      #pragma unroll
      for (int r = 0; r < 4; ++r) {
        int grow = mt + wm + mi * 16 + lq * 4 + r;
        int gcol = nt + wn + ni * 16 + l16;
        float v = acc[mi][ni][r];
        if (MODE == 1) {
          outb[((size_t)z * CCH + grow) * NPIX + gcol] = f2b(v + bias[grow]);
        } else {  // MODE 3
          if (gcol < 512)
            outb[(size_t)grow * CCH + gcol] = f2b((v + bias[gcol]) * alpha);
          else
            outb2[(size_t)grow * CCH + (gcol - 512)] = f2b(v + bias2[gcol - 512]);
        }
      }
}

// ---------- 4. fused QK + V projection GEMMs (one launch, 768 blocks) ----------
__global__ __launch_bounds__(256) void qkv_k(const u16* __restrict__ Ht,
                                             const u16* __restrict__ wb,
                                             const float* __restrict__ bq,
                                             const float* __restrict__ bk,
                                             const float* __restrict__ bv,
                                             u16* __restrict__ Qt, u16* __restrict__ Kt,
                                             u16* __restrict__ Vc, float alpha) {
  __shared__ __align__(16) u16 As[2][4096];
  __shared__ __align__(16) u16 Bs[2][4096];
  int blk = blockIdx.x;
  if (blk < 512) {        // QK: A=Ht flat, B=[wq;wk]
    gemm_body<3>(Ht, wb, bq, bk, Qt, Kt, alpha, blk & 63, blk >> 6, 0,
                 &As[0][0], &Bs[0][0]);
  } else {                // V: A=wv, B=Ht[z]
    int r = blk - 512;
    gemm_body<1>(wb + 2u * 262144u, Ht, bv, nullptr, Vc, nullptr, 1.0f,
                 r & 3, (r >> 2) & 31, r >> 7, &As[0][0], &Bs[0][0]);
  }
}

// ---------- 5. Flash attention (proven R6 structure — unchanged) ----------
__global__ __launch_bounds__(256, 2) void flash_k(const u16* __restrict__ Qt,
                                                  const u16* __restrict__ Kt,
                                                  const u16* __restrict__ Vc,
                                                  u16* __restrict__ sl0, u16* __restrict__ sl1,
                                                  float* __restrict__ mlp) {
  __shared__ __align__(16) char lds[65536];
  const int t = threadIdx.x, wv = t >> 6, l = t & 63;
  const int l16 = l & 15, lq = l >> 4;
  const int orig = blockIdx.x;
  const int gid = (orig & 7) * 64 + (orig >> 3);     // XCD-chunked remap (512%8==0)
  const int qx = gid & 31, grp = gid >> 5;
  const int hd = grp & 3, b = (grp >> 2) & 1, s = grp >> 3;
  const int qt0 = qx * 128 + wv * 32;

  const u16* Q = Qt + ((size_t)b * NPIX + qt0) * CCH + hd * HC;
  const u16* Kbase = Kt + (size_t)b * NPIX * CCH + hd * HC;          // [key][CCH]
  const u16* Vbase = Vc + (size_t)b * CCH * NPIX + (size_t)hd * HC * NPIX; // [ch][NPIX]
  u16* slab = (s == 0) ? sl0 : sl1;
  u16* Ob = slab + ((size_t)(b * NHEAD + hd) * NPIX + qt0) * HC;
  size_t mlR0 = (size_t)s * 32768 + (size_t)(b * NHEAD + hd) * NPIX + qt0;

  bf16x8 qf[2][4];
  #pragma unroll
  for (int mi = 0; mi < 2; ++mi)
    #pragma unroll
    for (int kk = 0; kk < 4; ++kk)
      qf[mi][kk] = *(const bf16x8*)(Q + (size_t)(mi * 16 + l16) * CCH + kk * 32 + lq * 8);

  const int m_beg = s * KVCHUNK;
  const int sw = (l16 & 7) << 4;                    // per-lane swizzle nibble
  const int vb2 = (lq & 1) * 32 + (lq >> 1) * 16;   // permuted key-base (permlane order)

  int kbase[4], vbase[2];
  #pragma unroll
  for (int kk = 0; kk < 4; ++kk) kbase[kk] = l16 * 256 + ((kk * 64 + lq * 16) ^ sw);
  #pragma unroll
  for (int ks = 0; ks < 2; ++ks) vbase[ks] = 32768 + l16 * 128 + ((ks * 64 + vb2) ^ sw);

  u32 kgo[4], vgo[4];
  #pragma unroll
  for (int j = 0; j < 4; ++j) {
    int g = j * 256 + t;
    { int row = g >> 4, src = ((g & 15) << 4) ^ ((row & 7) << 4);
      kgo[j] = (u32)row * CCH + (src >> 1); }
    { int row = g >> 3, src = ((g & 7) << 4) ^ ((row & 7) << 4);
      vgo[j] = (u32)row * NPIX + (src >> 1); }
  }

  const short one_bf = (short)0x3F80;               // bf16 1.0
  const bf16x8 vones = { one_bf, one_bf, one_bf, one_bf, one_bf, one_bf, one_bf, one_bf };

  f32x4 oacc[2][8] = {};
  f32x4 osum[2] = {};                               // row-sum of P (softmax denom), via MFMA

  {
    const u16* kg = Kbase + (size_t)m_beg * CCH;
    const u16* vg = Vbase + m_beg;
    #pragma unroll
    for (int j = 0; j < 4; ++j) {
      gl_lds16(kg + kgo[j], (u16*)lds + (j * 256 + t) * 8);
      gl_lds16(vg + vgo[j], (u16*)(lds + 32768) + (j * 256 + t) * 8);
    }
  }
  asm volatile("s_waitcnt vmcnt(0)" ::: "memory");
  __syncthreads();

  const int NT = KVCHUNK / 64;                      // 32 (even)

#define FLASH_BODY(CUR, M0, DOSTAGE)                                                   \
  {                                                                                    \
    if (DOSTAGE) {                                                                     \
      const u16* kg = Kbase + (size_t)((M0) + 64) * CCH;                               \
      const u16* vg = Vbase + ((M0) + 64);                                             \
      _Pragma("unroll")                                                                \
      for (int j = 0; j < 4; ++j) {                                                    \
        gl_lds16(kg + kgo[j], (u16*)(lds + ((CUR) ^ 1) * 16384) + (j * 256 + t) * 8);  \
        gl_lds16(vg + vgo[j], (u16*)(lds + 32768 + ((CUR) ^ 1) * 16384) + (j * 256 + t) * 8); \
      }                                                                                \
    }                                                                                  \
    f32x4 S[2][4] = {};                                                                \
    __builtin_amdgcn_s_setprio(1);                                                     \
    _Pragma("unroll")                                                                  \
    for (int kk = 0; kk < 4; ++kk)                                                     \
      _Pragma("unroll")                                                                \
      for (int mm = 0; mm < 4; ++mm) {                                                 \
        bf16x8 kf = *(const bf16x8*)(lds + kbase[kk] + mm * 4096 + (CUR) * 16384);     \
        S[0][mm] = MFMA16(kf, qf[0][kk], S[0][mm]);                                    \
        S[1][mm] = MFMA16(kf, qf[1][kk], S[1][mm]);                                    \
      }                                                                                \
    __builtin_amdgcn_s_setprio(0);                                                     \
    u32 pk[2][4][2];                                                                   \
    _Pragma("unroll")                                                                  \
    for (int mi = 0; mi < 2; ++mi) {                                                   \
      _Pragma("unroll")                                                                \
      for (int mm = 0; mm < 4; ++mm) {                                                 \
        f32x4 p;                                                                       \
        _Pragma("unroll")                                                              \
        for (int r = 0; r < 4; ++r) p[r] = exp2f(S[mi][mm][r]);                        \
        asm("v_cvt_pk_bf16_f32 %0, %1, %2" : "=v"(pk[mi][mm][0]) : "v"(p[0]), "v"(p[1])); \
        asm("v_cvt_pk_bf16_f32 %0, %1, %2" : "=v"(pk[mi][mm][1]) : "v"(p[2]), "v"(p[3])); \
      }                                                                                \
    }                                                                                  \
    bf16x8 pa[2][2];                                                                   \
    _Pragma("unroll")                                                                  \
    for (int mi = 0; mi < 2; ++mi)                                                     \
      _Pragma("unroll")                                                                \
      for (int ks = 0; ks < 2; ++ks) {                                                 \
        u32 a0 = pk[mi][2 * ks][0], a1 = pk[mi][2 * ks][1];                            \
        u32 b0 = pk[mi][2 * ks + 1][0], b1 = pk[mi][2 * ks + 1][1];                    \
        asm("v_permlane16_swap_b32 %0, %1" : "+v"(a0), "+v"(b0));                      \
        asm("v_permlane16_swap_b32 %0, %1" : "+v"(a1), "+v"(b1));                      \
        u32x4 w = { a0, a1, b0, b1 };                                                  \
        pa[mi][ks] = __builtin_bit_cast(bf16x8, w);                                    \
      }                                                                                \
    __builtin_amdgcn_s_setprio(1);                                                     \
    _Pragma("unroll")                                                                  \
    for (int ks = 0; ks < 2; ++ks) {                                                   \
      osum[0] = MFMA16(pa[0][ks], vones, osum[0]);                                     \
      osum[1] = MFMA16(pa[1][ks], vones, osum[1]);                                     \
      _Pragma("unroll")                                                                \
      for (int cc = 0; cc < 8; ++cc) {                                                 \
        bf16x8 vf = *(const bf16x8*)(lds + vbase[ks] + cc * 2048 + (CUR) * 16384);     \
        oacc[0][cc] = MFMA16(pa[0][ks], vf, oacc[0][cc]);                              \
        oacc[1][cc] = MFMA16(pa[1][ks], vf, oacc[1][cc]);                              \
      }                                                                                \
    }                                                                                  \
    __builtin_amdgcn_s_setprio(0);                                                     \
    asm volatile("s_waitcnt vmcnt(0)" ::: "memory");                                   \
    __syncthreads();                                                                   \
  }

  for (int it = 0; it < NT; it += 2) {
    FLASH_BODY(0, m_beg + it * 64, true)                    // NT even: it+1 < NT always
    FLASH_BODY(1, m_beg + it * 64 + 64, (it + 2 < NT))
  }
#undef FLASH_BODY

  // ---- epilogue: raw partial O + denominator l ----
  #pragma unroll
  for (int mi = 0; mi < 2; ++mi)
    #pragma unroll
    for (int cc = 0; cc < 8; ++cc)
      #pragma unroll
      for (int r = 0; r < 4; ++r)
        Ob[(size_t)(mi * 16 + lq * 4 + r) * HC + cc * 16 + l16] = f2b(oacc[mi][cc][r]);
  if (l16 == 0) {
    #pragma unroll
    for (int mi = 0; mi < 2; ++mi)
      #pragma unroll
      for (int r = 0; r < 4; ++r)
        mlp[mlR0 + mi * 16 + lq * 4 + r] = osum[mi][r];
  }
}

// ---------- 6. final GEMM with fused split-merge ----------
// out[z][o][q] = sum_c Wo[o][c] * O[c][q] + bo[o] + x[z][o][q],
// O[c][q] = (sl0+sl1)[(z*4+h)*4096+q][c&127] / l_h[q], h=c>>7.
// Running-rescale: process heads in order; entering head h scale acc by l_h/l_{h-1};
// epilogue divides by l_3. Both slabs staged via gl_lds16; 2x MFMA per frag.
__global__ __launch_bounds__(256) void fgemm_k(const u16* __restrict__ Wo,
                                               const u16* __restrict__ sl0,
                                               const u16* __restrict__ sl1,
                                               const float* __restrict__ ml,
                                               const float* __restrict__ bias,
                                               const float* __restrict__ resid,
                                               float* __restrict__ outf) {
  __shared__ __align__(16) u16 As[2][4096];
  __shared__ __align__(16) u16 B0[2][4096];
  __shared__ __align__(16) u16 B1[2][4096];
  const int t = threadIdx.x, l = t & 63, wv = t >> 6;
  const int l16 = l & 15, lq = l >> 4;
  const int mt = blockIdx.x * 128, nt = blockIdx.y * 128, z = blockIdx.z;
  const u16* Ap = Wo + (size_t)mt * CCH;
  const int wm = (wv >> 1) * 64, wn = (wv & 1) * 64;

  // per-(head, ni) softmax denominators for this thread's output columns
  float lsum[4][4];
  #pragma unroll
  for (int h = 0; h < 4; ++h)
    #pragma unroll
    for (int ni = 0; ni < 4; ++ni) {
      int gcol = nt + wn + ni * 16 + l16;
      int R = ((z * 4 + h) << 12) + gcol;
      lsum[h][ni] = ml[R] + ml[32768 + R];
    }

  f32x4 acc[4][4] = {};

  // ---- prologue: stage k=0 (head 0) into buf 0 ----
  #pragma unroll
  for (int j = 0; j < 2; ++j) {
    int idx = t + j * 256;
    int row = idx >> 2, kc = (idx & 3) * 8;
    gl_lds16(Ap + (size_t)row * CCH + kc, &As[0][0] + idx * 8);
    size_t srow = ((size_t)(z * 4) * NPIX + nt + row) * HC + kc;
    gl_lds16(sl0 + srow, &B0[0][0] + idx * 8);
    gl_lds16(sl1 + srow, &B1[0][0] + idx * 8);
  }
  asm volatile("s_waitcnt vmcnt(0)" ::: "memory");
  __syncthreads();

#define FG_BODY(CUR, K0, DOSTAGE)                                                     \
  {                                                                                   \
    if (DOSTAGE) {                                                                    \
      const int kn = (K0) + 32;                                                       \
      const int hn = kn >> 7, cn = kn & 127;                                          \
      _Pragma("unroll")                                                               \
      for (int j = 0; j < 2; ++j) {                                                   \
        int idx = t + j * 256;                                                        \
        int row = idx >> 2, kc = (idx & 3) * 8;                                       \
        gl_lds16(Ap + (size_t)row * CCH + kn + kc, &As[(CUR) ^ 1][0] + idx * 8);      \
        size_t srow = ((size_t)(z * 4 + hn) * NPIX + nt + row) * HC + cn + kc;        \
        gl_lds16(sl0 + srow, &B0[(CUR) ^ 1][0] + idx * 8);                            \
        gl_lds16(sl1 + srow, &B1[(CUR) ^ 1][0] + idx * 8);                            \
      }                                                                               \
    }                                                                                 \
    bf16x8 af[4], b0f[4], b1f[4];                                                     \
    _Pragma("unroll")                                                                 \
    for (int i = 0; i < 4; ++i) {                                                     \
      af[i]  = *(const bf16x8*)(&As[CUR][0] + (wm + i * 16 + l16) * 32 + lq * 8);     \
      b0f[i] = *(const bf16x8*)(&B0[CUR][0] + (wn + i * 16 + l16) * 32 + lq * 8);     \
      b1f[i] = *(const bf16x8*)(&B1[CUR][0] + (wn + i * 16 + l16) * 32 + lq * 8);     \
    }                                                                                 \
    _Pragma("unroll")                                                                 \
    for (int mi = 0; mi < 4; ++mi)                                                    \
      _Pragma("unroll")                                                               \
      for (int ni = 0; ni < 4; ++ni) {                                                \
        acc[mi][ni] = MFMA16(af[mi], b0f[ni], acc[mi][ni]);                           \
        acc[mi][ni] = MFMA16(af[mi], b1f[ni], acc[mi][ni]);                           \
      }                                                                               \
    asm volatile("s_waitcnt vmcnt(0)" ::: "memory");                                  \
    __syncthreads();                                                                  \
  }

  #pragma unroll
  for (int h = 0; h < 4; ++h) {
    if (h) {                                   // rescale running acc: *= l_h / l_{h-1}
      #pragma unroll
      for (int ni = 0; ni < 4; ++ni) {
        float rat = lsum[h][ni] / lsum[h - 1][ni];
        #pragma unroll
        for (int mi = 0; mi < 4; ++mi) acc[mi][ni] *= rat;
      }
    }
    FG_BODY(0, h * 128,      true)
    FG_BODY(1, h * 128 + 32, true)
    FG_BODY(0, h * 128 + 64, true)
    FG_BODY(1, h * 128 + 96, (h < 3))
  }
#undef FG_BODY

  #pragma unroll
  for (int ni = 0; ni < 4; ++ni) {
    float inv3 = 1.f / lsum[3][ni];
    int gcol = nt + wn + ni * 16 + l16;
    #pragma unroll
    for (int mi = 0; mi < 4; ++mi)
      #pragma unroll
      for (int r = 0; r < 4; ++r) {
        int grow = mt + wm + mi * 16 + lq * 4 + r;
        size_t off = ((size_t)z * CCH + grow) * NPIX + gcol;
        outf[off] = acc[mi][ni][r] * inv3 + bias[grow] + resid[off];
      }
  }
}

// ---------- launch ----------
extern "C" void kernel_launch(void* const* d_in, const int* in_sizes, int n_in,
                              void* d_out, int out_size, void* d_ws, size_t ws_size,
                              hipStream_t stream) {
  const float* x   = (const float*)d_in[0];
  const float* gns = (const float*)d_in[1];
  const float* gnb = (const float*)d_in[2];
  const float* wq  = (const float*)d_in[3];
  const float* bq  = (const float*)d_in[4];
  const float* wk  = (const float*)d_in[5];
  const float* bk  = (const float*)d_in[6];
  const float* wv  = (const float*)d_in[7];
  const float* bv  = (const float*)d_in[8];
  const float* wo  = (const float*)d_in[9];
  const float* bo  = (const float*)d_in[10];
  float* out = (float*)d_out;
  char* ws = (char*)d_ws;

  u16*   wb    = (u16*)ws;                          // 4 x 512x512 bf16 = 2 MiB ([wq;wk] contiguous)
  u16*   Ht    = (u16*)(ws + (size_t)( 2u << 20));  // [2][4096][512] (dead after QKV gemm)
  u16*   Qt    = (u16*)(ws + (size_t)(10u << 20));
  u16*   Kt    = (u16*)(ws + (size_t)(18u << 20));
  u16*   Vc    = (u16*)(ws + (size_t)(26u << 20));  // [2][512][4096]
  u16*   sl1   = (u16*)(ws + (size_t)(34u << 20));  // partial-O slab 1 (8 MiB)
  float* mlb   = (float*)(ws + (size_t)(42u << 20)); // [2][32768] f32 = 256 KiB
  float* stats = (float*)(ws + (size_t)(43u << 20)); // pstats [256][2]
  u16*   sl0   = Ht;                                 // Ht dead after QKV gemm

  prep_k    <<<dim3(1280, 1, 1), 256, 0, stream>>>(wq, wk, wv, wo, wb, x, stats);
  gn_norm_k <<<dim3(8, 64, 2),   256, 0, stream>>>(x, gns, gnb, stats, Ht);
  qkv_k     <<<dim3(768, 1, 1),  256, 0, stream>>>(Ht, wb, bq, bk, bv, Qt, Kt, Vc,
                                                   QK_SCALE * LOG2E);
  flash_k   <<<dim3(512, 1, 1),  256, 0, stream>>>(Qt, Kt, Vc, sl0, sl1, mlb);
  fgemm_k   <<<dim3(4, 32, 2),   256, 0, stream>>>(wb + 3u * 262144u, sl0, sl1, mlb,
                                                   bo, x, out);
}

// Round 15
// 143.132 us; speedup vs baseline: 3.1404x; 1.0305x over previous
//
#include <hip/hip_runtime.h>

// ---------- types ----------
typedef float    f32x4 __attribute__((ext_vector_type(4)));
typedef short    bf16x8 __attribute__((ext_vector_type(8)));
typedef unsigned short u16;
typedef u16      u16x4 __attribute__((ext_vector_type(4)));
typedef unsigned u32;
typedef u32      u32x4 __attribute__((ext_vector_type(4)));

#define MFMA16(a, b, c) __builtin_amdgcn_mfma_f32_16x16x32_bf16((a), (b), (c), 0, 0, 0)

#define CCH 512          // channels
#define NPIX 4096        // 64*64 pixels
#define NHEAD 4
#define HC 128           // head channels
#define NSPLIT 2         // flash-decoding KV splits
#define KVCHUNK (NPIX / NSPLIT)
#define QK_SCALE 0.04419417382415922f   // 1/sqrt(512)  (repo quirk: full C)
#define LOG2E 1.4426950408889634f

__device__ __forceinline__ u16 f2b(float f) {
  unsigned u = __builtin_bit_cast(unsigned, f);
  u += 0x7FFFu + ((u >> 16) & 1u);      // RNE
  return (u16)(u >> 16);
}
__device__ __forceinline__ float b2f(u16 b) {
  return __builtin_bit_cast(float, ((unsigned)b) << 16);
}

__device__ __forceinline__ void gl_lds16(const u16* g, u16* l) {
  __builtin_amdgcn_global_load_lds((const __attribute__((address_space(1))) void*)g,
                                   (__attribute__((address_space(3))) void*)l, 16, 0, 0);
}

// ---------- 1. fused: weights fp32->bf16 (blocks 0..1023) + GN partial stats (1024..2047) ----------
__global__ void prep_k(const float* __restrict__ w0, const float* __restrict__ w1,
                       const float* __restrict__ w2, const float* __restrict__ w3,
                       u16* __restrict__ dst,
                       const float* __restrict__ x, float* __restrict__ pstats) {
  int blk = blockIdx.x, t = threadIdx.x;
  if (blk < 1024) {                          // ---- weight convert ----
    int m = blk >> 8;
    const float* src = (m == 0) ? w0 : (m == 1) ? w1 : (m == 2) ? w2 : w3;
    int i = ((blk & 255) * 256 + t) * 4;
    f32x4 v = *(const f32x4*)(src + i);
    u16x4 o = { f2b(v[0]), f2b(v[1]), f2b(v[2]), f2b(v[3]) };
    *(u16x4*)(dst + (size_t)m * (CCH * CCH) + i) = o;
    return;
  }
  // ---- GroupNorm partial statistics: 16 chunks per (b, group) ----
  int sblk = blk - 1024;                     // 0..1023 = bg*16 + chunk
  const f32x4* p = (const f32x4*)(x + (size_t)sblk * 4096);
  int wv = t >> 6, l = t & 63;
  float s = 0.f, ss = 0.f;
  #pragma unroll
  for (int i = t; i < 1024; i += 256) {
    f32x4 v = p[i];
    s  += v[0] + v[1] + v[2] + v[3];
    ss += v[0]*v[0] + v[1]*v[1] + v[2]*v[2] + v[3]*v[3];
  }
  #pragma unroll
  for (int d = 32; d; d >>= 1) { s += __shfl_down(s, d, 64); ss += __shfl_down(ss, d, 64); }
  __shared__ float red[8];
  if (l == 0) { red[wv*2] = s; red[wv*2+1] = ss; }
  __syncthreads();
  if (t == 0) {
    pstats[sblk*2]   = red[0] + red[2] + red[4] + red[6];
    pstats[sblk*2+1] = red[1] + red[3] + red[5] + red[7];
  }
}

// ---------- 2. GN apply + transpose ----------
__global__ void gn_norm_k(const float* __restrict__ x, const float* __restrict__ gns,
                          const float* __restrict__ gnb, const float* __restrict__ pstats,
                          u16* __restrict__ Ht) {
  int t = threadIdx.x;
  int ct = blockIdx.x * 64, nt = blockIdx.y * 64, b = blockIdx.z;
  int c0 = ct + (t & 15) * 4;
  int n0 = nt + (t >> 4) * 4;
  const float* xb = x + ((size_t)b * CCH + c0) * NPIX + n0;
  int g = b * 32 + (c0 >> 4);
  const f32x4* ps = (const f32x4*)(pstats + g * 32);   // 16 chunks x 2 floats
  float s = 0.f, ss = 0.f;
  #pragma unroll
  for (int j = 0; j < 8; ++j) {
    f32x4 v = ps[j];
    s  += v[0] + v[2];
    ss += v[1] + v[3];
  }
  float mean = s * (1.f/65536.f);
  float var  = ss * (1.f/65536.f) - mean*mean;
  float rstd = rsqrtf(var + 1e-6f);
  f32x4 rows[4];
  #pragma unroll
  for (int j = 0; j < 4; ++j) {
    f32x4 v = *(const f32x4*)(xb + (size_t)j * NPIX);
    float a  = rstd * gns[c0 + j];
    float bb = gnb[c0 + j] - mean * a;
    rows[j] = v * a + bb;
  }
  #pragma unroll
  for (int i = 0; i < 4; ++i) {
    u16x4 o = { f2b(rows[0][i]), f2b(rows[1][i]), f2b(rows[2][i]), f2b(rows[3][i]) };
    *(u16x4*)(Ht + ((size_t)b * NPIX + n0 + i) * CCH + c0) = o;
  }
}

// ---------- 3. NT GEMM body, 128x128 tiles, double-buffered (proven R13 structure) ----------
// MODE 1: A=W, B=Ht[z]           -> outb[z][row=o][col=pix], bias[row]
// MODE 3: A=Ht flat [8192][512], B=[wq;wk] stacked [1024][512]
//         gcol<512 -> outb=Qt (alpha, bias) ; else outb2=Kt (bias2)
template<int MODE>
__device__ __forceinline__ void gemm_body(const u16* __restrict__ A,
                                          const u16* __restrict__ B,
                                          const float* __restrict__ bias,
                                          const float* __restrict__ bias2,
                                          u16* __restrict__ outb,
                                          u16* __restrict__ outb2,
                                          float alpha,
                                          int bx, int by, int z,
                                          u16* As, u16* Bs) {   // each [2][4096]
  const int t = threadIdx.x, l = t & 63, wv = t >> 6;
  const int l16 = l & 15, lq = l >> 4;
  const int mt = bx * 128, nt = by * 128;
  const u16* Ap = A + (size_t)mt * CCH;
  const u16* Bp = (MODE == 3) ? (B + (size_t)nt * CCH)
                              : (B + ((size_t)z * NPIX + nt) * CCH);
  const int wm = (wv >> 1) * 64, wn = (wv & 1) * 64;
  f32x4 acc[4][4] = {};

  // ---- prologue: stage k=0 into buf 0 ----
  #pragma unroll
  for (int j = 0; j < 2; ++j) {
    int idx = t + j * 256;
    int row = idx >> 2, kc = (idx & 3) * 8;
    gl_lds16(Ap + (size_t)row * CCH + kc, As + idx * 8);
    gl_lds16(Bp + (size_t)row * CCH + kc, Bs + idx * 8);
  }
  asm volatile("s_waitcnt vmcnt(0)" ::: "memory");
  __syncthreads();

#define GEMM_BODY(CUR, K0, DOSTAGE)                                                   \
  {                                                                                   \
    if (DOSTAGE) {                                                                    \
      _Pragma("unroll")                                                               \
      for (int j = 0; j < 2; ++j) {                                                   \
        int idx = t + j * 256;                                                        \
        int row = idx >> 2, kc = (idx & 3) * 8;                                       \
        gl_lds16(Ap + (size_t)row * CCH + (K0) + 32 + kc, As + ((CUR) ^ 1) * 4096 + idx * 8); \
        gl_lds16(Bp + (size_t)row * CCH + (K0) + 32 + kc, Bs + ((CUR) ^ 1) * 4096 + idx * 8); \
      }                                                                               \
    }                                                                                 \
    bf16x8 af[4], bfr[4];                                                             \
    _Pragma("unroll")                                                                 \
    for (int i = 0; i < 4; ++i) {                                                     \
      af[i]  = *(const bf16x8*)(As + (CUR) * 4096 + (wm + i * 16 + l16) * 32 + lq * 8); \
      bfr[i] = *(const bf16x8*)(Bs + (CUR) * 4096 + (wn + i * 16 + l16) * 32 + lq * 8); \
    }                                                                                 \
    _Pragma("unroll")                                                                 \
    for (int mi = 0; mi < 4; ++mi)                                                    \
      _Pragma("unroll")                                                               \
      for (int ni = 0; ni < 4; ++ni)                                                  \
        acc[mi][ni] = MFMA16(af[mi], bfr[ni], acc[mi][ni]);                           \
    asm volatile("s_waitcnt vmcnt(0)" ::: "memory");                                  \
    __syncthreads();                                                                  \
  }

  for (int k0 = 0; k0 < CCH; k0 += 64) {
    GEMM_BODY(0, k0, true)
    GEMM_BODY(1, k0 + 32, (k0 + 64 < CCH))
  }
#undef GEMM_BODY

  #pragma unroll
  for (int mi = 0; mi < 4; ++mi)
    #pragma unroll
    for (int ni = 0; ni < 4; ++ni)
      #pragma unroll
      for (int r = 0; r < 4; ++r) {
        int grow = mt + wm + mi * 16 + lq * 4 + r;
        int gcol = nt + wn + ni * 16 + l16;
        float v = acc[mi][ni][r];
        if (MODE == 1) {
          outb[((size_t)z * CCH + grow) * NPIX + gcol] = f2b(v + bias[grow]);
        } else {  // MODE 3
          if (gcol < 512)
            outb[(size_t)grow * CCH + gcol] = f2b((v + bias[gcol]) * alpha);
          else
            outb2[(size_t)grow * CCH + (gcol - 512)] = f2b(v + bias2[gcol - 512]);
        }
      }
}

// ---------- 4. fused QK + V projection GEMMs (one launch, 768 blocks) ----------
__global__ __launch_bounds__(256) void qkv_k(const u16* __restrict__ Ht,
                                             const u16* __restrict__ wb,
                                             const float* __restrict__ bq,
                                             const float* __restrict__ bk,
                                             const float* __restrict__ bv,
                                             u16* __restrict__ Qt, u16* __restrict__ Kt,
                                             u16* __restrict__ Vc, float alpha) {
  __shared__ __align__(16) u16 As[2][4096];
  __shared__ __align__(16) u16 Bs[2][4096];
  int blk = blockIdx.x;
  if (blk < 512) {        // QK: A=Ht flat, B=[wq;wk]
    gemm_body<3>(Ht, wb, bq, bk, Qt, Kt, alpha, blk & 63, blk >> 6, 0,
                 &As[0][0], &Bs[0][0]);
  } else {                // V: A=wv, B=Ht[z]
    int r = blk - 512;
    gemm_body<1>(wb + 2u * 262144u, Ht, bv, nullptr, Vc, nullptr, 1.0f,
                 r & 3, (r >> 2) & 31, r >> 7, &As[0][0], &Bs[0][0]);
  }
}

// ---------- 5. Flash attention (proven R6 structure — unchanged) ----------
__global__ __launch_bounds__(256, 2) void flash_k(const u16* __restrict__ Qt,
                                                  const u16* __restrict__ Kt,
                                                  const u16* __restrict__ Vc,
                                                  u16* __restrict__ sl0, u16* __restrict__ sl1,
                                                  float* __restrict__ mlp) {
  __shared__ __align__(16) char lds[65536];
  const int t = threadIdx.x, wv = t >> 6, l = t & 63;
  const int l16 = l & 15, lq = l >> 4;
  const int orig = blockIdx.x;
  const int gid = (orig & 7) * 64 + (orig >> 3);     // XCD-chunked remap (512%8==0)
  const int qx = gid & 31, grp = gid >> 5;
  const int hd = grp & 3, b = (grp >> 2) & 1, s = grp >> 3;
  const int qt0 = qx * 128 + wv * 32;

  const u16* Q = Qt + ((size_t)b * NPIX + qt0) * CCH + hd * HC;
  const u16* Kbase = Kt + (size_t)b * NPIX * CCH + hd * HC;          // [key][CCH]
  const u16* Vbase = Vc + (size_t)b * CCH * NPIX + (size_t)hd * HC * NPIX; // [ch][NPIX]
  u16* slab = (s == 0) ? sl0 : sl1;
  u16* Ob = slab + ((size_t)(b * NHEAD + hd) * NPIX + qt0) * HC;
  size_t mlR0 = (size_t)s * 32768 + (size_t)(b * NHEAD + hd) * NPIX + qt0;

  bf16x8 qf[2][4];
  #pragma unroll
  for (int mi = 0; mi < 2; ++mi)
    #pragma unroll
    for (int kk = 0; kk < 4; ++kk)
      qf[mi][kk] = *(const bf16x8*)(Q + (size_t)(mi * 16 + l16) * CCH + kk * 32 + lq * 8);

  const int m_beg = s * KVCHUNK;
  const int sw = (l16 & 7) << 4;                    // per-lane swizzle nibble
  const int vb2 = (lq & 1) * 32 + (lq >> 1) * 16;   // permuted key-base (permlane order)

  int kbase[4], vbase[2];
  #pragma unroll
  for (int kk = 0; kk < 4; ++kk) kbase[kk] = l16 * 256 + ((kk * 64 + lq * 16) ^ sw);
  #pragma unroll
  for (int ks = 0; ks < 2; ++ks) vbase[ks] = 32768 + l16 * 128 + ((ks * 64 + vb2) ^ sw);

  u32 kgo[4], vgo[4];
  #pragma unroll
  for (int j = 0; j < 4; ++j) {
    int g = j * 256 + t;
    { int row = g >> 4, src = ((g & 15) << 4) ^ ((row & 7) << 4);
      kgo[j] = (u32)row * CCH + (src >> 1); }
    { int row = g >> 3, src = ((g & 7) << 4) ^ ((row & 7) << 4);
      vgo[j] = (u32)row * NPIX + (src >> 1); }
  }

  const short one_bf = (short)0x3F80;               // bf16 1.0
  const bf16x8 vones = { one_bf, one_bf, one_bf, one_bf, one_bf, one_bf, one_bf, one_bf };

  f32x4 oacc[2][8] = {};
  f32x4 osum[2] = {};                               // row-sum of P (softmax denom), via MFMA

  {
    const u16* kg = Kbase + (size_t)m_beg * CCH;
    const u16* vg = Vbase + m_beg;
    #pragma unroll
    for (int j = 0; j < 4; ++j) {
      gl_lds16(kg + kgo[j], (u16*)lds + (j * 256 + t) * 8);
      gl_lds16(vg + vgo[j], (u16*)(lds + 32768) + (j * 256 + t) * 8);
    }
  }
  asm volatile("s_waitcnt vmcnt(0)" ::: "memory");
  __syncthreads();

  const int NT = KVCHUNK / 64;                      // 32 (even)

#define FLASH_BODY(CUR, M0, DOSTAGE)                                                   \
  {                                                                                    \
    if (DOSTAGE) {                                                                     \
      const u16* kg = Kbase + (size_t)((M0) + 64) * CCH;                               \
      const u16* vg = Vbase + ((M0) + 64);                                             \
      _Pragma("unroll")                                                                \
      for (int j = 0; j < 4; ++j) {                                                    \
        gl_lds16(kg + kgo[j], (u16*)(lds + ((CUR) ^ 1) * 16384) + (j * 256 + t) * 8);  \
        gl_lds16(vg + vgo[j], (u16*)(lds + 32768 + ((CUR) ^ 1) * 16384) + (j * 256 + t) * 8); \
      }                                                                                \
    }                                                                                  \
    f32x4 S[2][4] = {};                                                                \
    __builtin_amdgcn_s_setprio(1);                                                     \
    _Pragma("unroll")                                                                  \
    for (int kk = 0; kk < 4; ++kk)                                                     \
      _Pragma("unroll")                                                                \
      for (int mm = 0; mm < 4; ++mm) {                                                 \
        bf16x8 kf = *(const bf16x8*)(lds + kbase[kk] + mm * 4096 + (CUR) * 16384);     \
        S[0][mm] = MFMA16(kf, qf[0][kk], S[0][mm]);                                    \
        S[1][mm] = MFMA16(kf, qf[1][kk], S[1][mm]);                                    \
      }                                                                                \
    __builtin_amdgcn_s_setprio(0);                                                     \
    u32 pk[2][4][2];                                                                   \
    _Pragma("unroll")                                                                  \
    for (int mi = 0; mi < 2; ++mi) {                                                   \
      _Pragma("unroll")                                                                \
      for (int mm = 0; mm < 4; ++mm) {                                                 \
        f32x4 p;                                                                       \
        _Pragma("unroll")                                                              \
        for (int r = 0; r < 4; ++r) p[r] = exp2f(S[mi][mm][r]);                        \
        asm("v_cvt_pk_bf16_f32 %0, %1, %2" : "=v"(pk[mi][mm][0]) : "v"(p[0]), "v"(p[1])); \
        asm("v_cvt_pk_bf16_f32 %0, %1, %2" : "=v"(pk[mi][mm][1]) : "v"(p[2]), "v"(p[3])); \
      }                                                                                \
    }                                                                                  \
    bf16x8 pa[2][2];                                                                   \
    _Pragma("unroll")                                                                  \
    for (int mi = 0; mi < 2; ++mi)                                                     \
      _Pragma("unroll")                                                                \
      for (int ks = 0; ks < 2; ++ks) {                                                 \
        u32 a0 = pk[mi][2 * ks][0], a1 = pk[mi][2 * ks][1];                            \
        u32 b0 = pk[mi][2 * ks + 1][0], b1 = pk[mi][2 * ks + 1][1];                    \
        asm("v_permlane16_swap_b32 %0, %1" : "+v"(a0), "+v"(b0));                      \
        asm("v_permlane16_swap_b32 %0, %1" : "+v"(a1), "+v"(b1));                      \
        u32x4 w = { a0, a1, b0, b1 };                                                  \
        pa[mi][ks] = __builtin_bit_cast(bf16x8, w);                                    \
      }                                                                                \
    __builtin_amdgcn_s_setprio(1);                                                     \
    _Pragma("unroll")                                                                  \
    for (int ks = 0; ks < 2; ++ks) {                                                   \
      osum[0] = MFMA16(pa[0][ks], vones, osum[0]);                                     \
      osum[1] = MFMA16(pa[1][ks], vones, osum[1]);                                     \
      _Pragma("unroll")                                                                \
      for (int cc = 0; cc < 8; ++cc) {                                                 \
        bf16x8 vf = *(const bf16x8*)(lds + vbase[ks] + cc * 2048 + (CUR) * 16384);     \
        oacc[0][cc] = MFMA16(pa[0][ks], vf, oacc[0][cc]);                              \
        oacc[1][cc] = MFMA16(pa[1][ks], vf, oacc[1][cc]);                              \
      }                                                                                \
    }                                                                                  \
    __builtin_amdgcn_s_setprio(0);                                                     \
    asm volatile("s_waitcnt vmcnt(0)" ::: "memory");                                   \
    __syncthreads();                                                                   \
  }

  for (int it = 0; it < NT; it += 2) {
    FLASH_BODY(0, m_beg + it * 64, true)                    // NT even: it+1 < NT always
    FLASH_BODY(1, m_beg + it * 64 + 64, (it + 2 < NT))
  }
#undef FLASH_BODY

  // ---- epilogue: raw partial O + denominator l ----
  #pragma unroll
  for (int mi = 0; mi < 2; ++mi)
    #pragma unroll
    for (int cc = 0; cc < 8; ++cc)
      #pragma unroll
      for (int r = 0; r < 4; ++r)
        Ob[(size_t)(mi * 16 + lq * 4 + r) * HC + cc * 16 + l16] = f2b(oacc[mi][cc][r]);
  if (l16 == 0) {
    #pragma unroll
    for (int mi = 0; mi < 2; ++mi)
      #pragma unroll
      for (int r = 0; r < 4; ++r)
        mlp[mlR0 + mi * 16 + lq * 4 + r] = osum[mi][r];
  }
}

// ---------- 6. final GEMM with fused split-merge, 128M x 64N tiles ----------
// out[z][o][q] = sum_c Wo[o][c] * O[c][q] + bo[o] + x[z][o][q],
// O[c][q] = (sl0+sl1)[(z*4+h)*4096+q][c&127] / l_h[q], h=c>>7.
// Running-rescale across heads; epilogue divides by l_3.
__global__ __launch_bounds__(256) void fgemm_k(const u16* __restrict__ Wo,
                                               const u16* __restrict__ sl0,
                                               const u16* __restrict__ sl1,
                                               const float* __restrict__ ml,
                                               const float* __restrict__ bias,
                                               const float* __restrict__ resid,
                                               float* __restrict__ outf) {
  __shared__ __align__(16) u16 As[2][4096];
  __shared__ __align__(16) u16 B0[2][2048];
  __shared__ __align__(16) u16 B1[2][2048];
  const int t = threadIdx.x, l = t & 63, wv = t >> 6;
  const int l16 = l & 15, lq = l >> 4;
  const int mt = blockIdx.x * 128, nt = blockIdx.y * 64, z = blockIdx.z;
  const u16* Ap = Wo + (size_t)mt * CCH;
  const int wm = (wv >> 1) * 64, wn = (wv & 1) * 32;

  // per-(head, ni) softmax denominators for this thread's output columns
  float lsum[4][2];
  #pragma unroll
  for (int h = 0; h < 4; ++h)
    #pragma unroll
    for (int ni = 0; ni < 2; ++ni) {
      int gcol = nt + wn + ni * 16 + l16;
      int R = ((z * 4 + h) << 12) + gcol;
      lsum[h][ni] = ml[R] + ml[32768 + R];
    }

  f32x4 acc[4][2] = {};

  // ---- prologue: stage k=0 (head 0) into buf 0 ----
  #pragma unroll
  for (int j = 0; j < 2; ++j) {
    int idx = t + j * 256;
    int row = idx >> 2, kc = (idx & 3) * 8;
    gl_lds16(Ap + (size_t)row * CCH + kc, &As[0][0] + idx * 8);
  }
  {
    int row = t >> 2, kc = (t & 3) * 8;
    size_t srow = ((size_t)(z * 4) * NPIX + nt + row) * HC + kc;
    gl_lds16(sl0 + srow, &B0[0][0] + t * 8);
    gl_lds16(sl1 + srow, &B1[0][0] + t * 8);
  }
  asm volatile("s_waitcnt vmcnt(0)" ::: "memory");
  __syncthreads();

#define FG_BODY(CUR, K0, DOSTAGE)                                                     \
  {                                                                                   \
    if (DOSTAGE) {                                                                    \
      const int kn = (K0) + 32;                                                       \
      const int hn = kn >> 7, cn = kn & 127;                                          \
      _Pragma("unroll")                                                               \
      for (int j = 0; j < 2; ++j) {                                                   \
        int idx = t + j * 256;                                                        \
        int row = idx >> 2, kc = (idx & 3) * 8;                                       \
        gl_lds16(Ap + (size_t)row * CCH + kn + kc, &As[(CUR) ^ 1][0] + idx * 8);      \
      }                                                                               \
      {                                                                               \
        int row = t >> 2, kc = (t & 3) * 8;                                           \
        size_t srow = ((size_t)(z * 4 + hn) * NPIX + nt + row) * HC + cn + kc;        \
        gl_lds16(sl0 + srow, &B0[(CUR) ^ 1][0] + t * 8);                              \
        gl_lds16(sl1 + srow, &B1[(CUR) ^ 1][0] + t * 8);                              \
      }                                                                               \
    }                                                                                 \
    bf16x8 af[4], b0f[2], b1f[2];                                                     \
    _Pragma("unroll")                                                                 \
    for (int i = 0; i < 4; ++i)                                                       \
      af[i]  = *(const bf16x8*)(&As[CUR][0] + (wm + i * 16 + l16) * 32 + lq * 8);     \
    _Pragma("unroll")                                                                 \
    for (int i = 0; i < 2; ++i) {                                                     \
      b0f[i] = *(const bf16x8*)(&B0[CUR][0] + (wn + i * 16 + l16) * 32 + lq * 8);     \
      b1f[i] = *(const bf16x8*)(&B1[CUR][0] + (wn + i * 16 + l16) * 32 + lq * 8);     \
    }                                                                                 \
    _Pragma("unroll")                                                                 \
    for (int mi = 0; mi < 4; ++mi)                                                    \
      _Pragma("unroll")                                                               \
      for (int ni = 0; ni < 2; ++ni) {                                                \
        acc[mi][ni] = MFMA16(af[mi], b0f[ni], acc[mi][ni]);                           \
        acc[mi][ni] = MFMA16(af[mi], b1f[ni], acc[mi][ni]);                           \
      }                                                                               \
    asm volatile("s_waitcnt vmcnt(0)" ::: "memory");                                  \
    __syncthreads();                                                                  \
  }

  #pragma unroll
  for (int h = 0; h < 4; ++h) {
    if (h) {                                   // rescale running acc: *= l_h / l_{h-1}
      #pragma unroll
      for (int ni = 0; ni < 2; ++ni) {
        float rat = lsum[h][ni] / lsum[h - 1][ni];
        #pragma unroll
        for (int mi = 0; mi < 4; ++mi) acc[mi][ni] *= rat;
      }
    }
    FG_BODY(0, h * 128,      true)
    FG_BODY(1, h * 128 + 32, true)
    FG_BODY(0, h * 128 + 64, true)
    FG_BODY(1, h * 128 + 96, (h < 3))
  }
#undef FG_BODY

  #pragma unroll
  for (int ni = 0; ni < 2; ++ni) {
    float inv3 = 1.f / lsum[3][ni];
    int gcol = nt + wn + ni * 16 + l16;
    #pragma unroll
    for (int mi = 0; mi < 4; ++mi)
      #pragma unroll
      for (int r = 0; r < 4; ++r) {
        int grow = mt + wm + mi * 16 + lq * 4 + r;
        size_t off = ((size_t)z * CCH + grow) * NPIX + gcol;
        outf[off] = acc[mi][ni][r] * inv3 + bias[grow] + resid[off];
      }
  }
}

// ---------- launch ----------
extern "C" void kernel_launch(void* const* d_in, const int* in_sizes, int n_in,
                              void* d_out, int out_size, void* d_ws, size_t ws_size,
                              hipStream_t stream) {
  const float* x   = (const float*)d_in[0];
  const float* gns = (const float*)d_in[1];
  const float* gnb = (const float*)d_in[2];
  const float* wq  = (const float*)d_in[3];
  const float* bq  = (const float*)d_in[4];
  const float* wk  = (const float*)d_in[5];
  const float* bk  = (const float*)d_in[6];
  const float* wv  = (const float*)d_in[7];
  const float* bv  = (const float*)d_in[8];
  const float* wo  = (const float*)d_in[9];
  const float* bo  = (const float*)d_in[10];
  float* out = (float*)d_out;
  char* ws = (char*)d_ws;

  u16*   wb    = (u16*)ws;                          // 4 x 512x512 bf16 = 2 MiB ([wq;wk] contiguous)
  u16*   Ht    = (u16*)(ws + (size_t)( 2u << 20));  // [2][4096][512] (dead after QKV gemm)
  u16*   Qt    = (u16*)(ws + (size_t)(10u << 20));
  u16*   Kt    = (u16*)(ws + (size_t)(18u << 20));
  u16*   Vc    = (u16*)(ws + (size_t)(26u << 20));  // [2][512][4096]
  u16*   sl1   = (u16*)(ws + (size_t)(34u << 20));  // partial-O slab 1 (8 MiB)
  float* mlb   = (float*)(ws + (size_t)(42u << 20)); // [2][32768] f32 = 256 KiB
  float* stats = (float*)(ws + (size_t)(43u << 20)); // pstats [1024][2]
  u16*   sl0   = Ht;                                 // Ht dead after QKV gemm

  prep_k    <<<dim3(2048, 1, 1), 256, 0, stream>>>(wq, wk, wv, wo, wb, x, stats);
  gn_norm_k <<<dim3(8, 64, 2),   256, 0, stream>>>(x, gns, gnb, stats, Ht);
  qkv_k     <<<dim3(768, 1, 1),  256, 0, stream>>>(Ht, wb, bq, bk, bv, Qt, Kt, Vc,
                                                   QK_SCALE * LOG2E);
  flash_k   <<<dim3(512, 1, 1),  256, 0, stream>>>(Qt, Kt, Vc, sl0, sl1, mlb);
  fgemm_k   <<<dim3(4, 64, 2),   256, 0, stream>>>(wb + 3u * 262144u, sl0, sl1, mlb,
                                                   bo, x, out);
}